// Round 2
// baseline (6496.559 us; speedup 1.0000x reference)
//
#include <hip/hip_runtime.h>

#define B_ 32
#define P_ 196
#define D_ 2048
#define A_ 512
#define E_ 512
#define H_ 512
#define V_ 10000
#define L_ 21
#define T_ 20
#define N1 14608            /* 512 att2 + 2048 gate + 2048 ghh + 10000 fc */

struct KParams {
  const float* encoder_out; const int* captions; const int* cap_lens;
  const float* enc_att_w; const float* enc_att_b;
  const float* dec_att_w; const float* dec_att_b;
  const float* full_att_w; const float* full_att_b;
  const float* emb;
  const float* init_h_w; const float* init_h_b;
  const float* init_c_w; const float* init_c_b;
  const float* f_beta_w; const float* f_beta_b;
  const float* lstm_w_ih; const float* lstm_w_hh; const float* lstm_b;
  const float* fc_w; const float* fc_b;
  float* out_preds; float* out_caps; float* out_declens; float* out_alphas; float* out_sortind;
  int* sort_ind; int* declen; int* caps_s;
  unsigned short* h_bf16; float* c; float* mean; float* h0part;
  unsigned short* enc_bf16; unsigned short* waw_bf16; unsigned short* wihE_bf16; unsigned short* embs_bf16;
  unsigned short* att1; unsigned short* Wt; unsigned short* Wt2; unsigned short* awe_bf16;
  float* gpre; float* s1out; float* gpart;
  int* sync;
};

__device__ __forceinline__ unsigned short f2bf(float x){
  unsigned u = __float_as_uint(x);
  unsigned r = ((u >> 16) & 1u) + 0x7FFFu;
  return (unsigned short)((u + r) >> 16);
}
__device__ __forceinline__ unsigned pack2(float a, float b){
  return (unsigned)f2bf(a) | ((unsigned)f2bf(b) << 16);
}
__device__ __forceinline__ float bf2f(unsigned u16){ return __uint_as_float(u16 << 16); }
__device__ __forceinline__ float sigm(float x){ return 1.f/(1.f + __expf(-x)); }
__device__ __forceinline__ float tanh_f(float x){ return 1.f - 2.f/(__expf(2.f*x) + 1.f); }

// ---------------- prologue kernels ----------------

__global__ void k_meta(KParams p){
  __shared__ int len[32], sidx[32], sdecl[32];
  int tid = threadIdx.x;
  if (tid < 32) len[tid] = p.cap_lens[tid];
  __syncthreads();
  if (tid == 0){
    bool used[32];
    for (int i = 0; i < 32; i++) used[i] = false;
    for (int r = 0; r < 32; r++){
      int best = -1, bl = -2;
      for (int i = 0; i < 32; i++) if (!used[i] && len[i] > bl){ bl = len[i]; best = i; }
      used[best] = true; sidx[r] = best; sdecl[r] = bl - 1;
    }
  }
  __syncthreads();
  if (tid < 32){
    p.sort_ind[tid] = sidx[tid]; p.out_sortind[tid] = (float)sidx[tid];
    p.declen[tid]   = sdecl[tid]; p.out_declens[tid] = (float)sdecl[tid];
  }
  for (int idx = tid; idx < B_*L_; idx += 64){
    int b = idx / L_, l = idx - b*L_;
    int cv = p.captions[sidx[b]*L_ + l];
    p.caps_s[idx] = cv; p.out_caps[idx] = (float)cv;
  }
}

__global__ void k_encbf(KParams p){ // sorted encoder -> bf16
  int q = blockIdx.x*256 + threadIdx.x;
  const int QB = P_*D_/4;
  int b = q / QB; int r = q - b*QB;
  float4 v = ((const float4*)(p.encoder_out + (size_t)p.sort_ind[b]*(P_*D_)))[r];
  ((uint2*)p.enc_bf16)[q] = make_uint2(pack2(v.x, v.y), pack2(v.z, v.w));
}

__global__ void k_wbf(KParams p){ // enc_att_w and lstm_w_ih[:512] -> bf16 (row-major, GEMM B operands)
  int q = blockIdx.x*256 + threadIdx.x; // 524288 quads
  const float4* src; uint2* dst; int qq;
  if (q < 262144){ src = (const float4*)p.enc_att_w; dst = (uint2*)p.waw_bf16;  qq = q; }
  else           { src = (const float4*)p.lstm_w_ih; dst = (uint2*)p.wihE_bf16; qq = q - 262144; }
  float4 v = src[qq];
  dst[qq] = make_uint2(pack2(v.x, v.y), pack2(v.z, v.w));
}

// transpose fp32 [R][C] -> bf16 [C][R]
__global__ void k_transpose(const float* src, unsigned short* dst, int R, int C){
  __shared__ float tl[32][33];
  int tilesC = (C + 31) >> 5;
  int tr = blockIdx.x / tilesC, tc = blockIdx.x - tr*tilesC;
  int r0 = tr << 5, c0 = tc << 5;
  int tid = threadIdx.x;
  int r = tid >> 3, cs = (tid & 7) << 2;
  #pragma unroll
  for (int i = 0; i < 4; i++){
    int c = c0 + cs + i;
    tl[r][cs + i] = (c < C) ? src[(size_t)(r0 + r)*C + c] : 0.f;
  }
  __syncthreads();
  int c = tid >> 3, rs = (tid & 7) << 2;
  if (c0 + c < C){
    unsigned lo = pack2(tl[rs][c], tl[rs+1][c]);
    unsigned hi = pack2(tl[rs+2][c], tl[rs+3][c]);
    *(uint2*)(dst + (size_t)(c0 + c)*R + r0 + rs) = make_uint2(lo, hi);
  }
}

__global__ void k_mean(KParams p){
  int idx = blockIdx.x*256 + threadIdx.x; // 32768
  int b = idx >> 10, d2 = idx & 1023;
  const unsigned short* e = p.enc_bf16 + (size_t)b*P_*D_ + d2*2;
  float s0 = 0.f, s1 = 0.f;
  for (int pp = 0; pp < P_; ++pp){
    unsigned u = *(const unsigned*)(e + (size_t)pp*D_);
    s0 += bf2f(u & 0xffffu); s1 += bf2f(u >> 16);
  }
  const float inv = 1.f/196.f;
  p.mean[b*D_ + d2*2]     = s0*inv;
  p.mean[b*D_ + d2*2 + 1] = s1*inv;
}

__global__ void k_h0c0(KParams p){
  __shared__ float mlds[32*128];
  int tid = threadIdx.x;
  int tile = blockIdx.x & 3, kp = blockIdx.x >> 2;
  int k0 = kp*128;
  {
    int tb = tid >> 3, ti = tid & 7;
    const float4* src = (const float4*)(p.mean + tb*D_ + k0);
    float4* dst = (float4*)(mlds + tb*128);
    #pragma unroll
    for (int i = 0; i < 4; i++) dst[ti + 8*i] = src[ti + 8*i];
  }
  __syncthreads();
  int col = tile*256 + tid;
  const float* wb = (col < 512 ? p.init_h_w + col : p.init_c_w + (col - 512)) + (size_t)k0*H_;
  float acc[32];
  #pragma unroll
  for (int i = 0; i < 32; i++) acc[i] = 0.f;
  for (int k = 0; k < 128; k += 4){
    float w0 = wb[0], w1 = wb[H_], w2 = wb[2*H_], w3 = wb[3*H_];
    wb += 4*H_;
    #pragma unroll
    for (int i = 0; i < 32; i++){
      float4 hv = *(const float4*)(mlds + i*128 + k);
      acc[i] += hv.x*w0 + hv.y*w1 + hv.z*w2 + hv.w*w3;
    }
  }
  float* op = p.h0part + (size_t)kp*32768 + col;
  #pragma unroll
  for (int i = 0; i < 32; i++) op[i*1024] = acc[i];
}

__global__ void k_h0c0red(KParams p){
  int idx = blockIdx.x*256 + threadIdx.x; // 32768
  int b = idx >> 10, col = idx & 1023;
  float s = 0.f;
  #pragma unroll
  for (int kp = 0; kp < 16; kp++) s += p.h0part[(size_t)kp*32768 + b*1024 + col];
  if (col < 512) p.h_bf16[b*512 + col] = f2bf(s + p.init_h_b[col]);
  else           p.c[b*512 + col - 512] = s + p.init_c_b[col - 512];
}

__global__ void k_embs(KParams p){
  int q = blockIdx.x*256 + threadIdx.x; // 81920 quads
  int row = q >> 7, qi = q & 127;
  int t = row >> 5, b = row & 31;
  int cap = p.caps_s[b*L_ + t];
  float4 v = ((const float4*)(p.emb + (size_t)cap*E_))[qi];
  ((uint2*)p.embs_bf16)[q] = make_uint2(pack2(v.x, v.y), pack2(v.z, v.w));
}

// ---------------- generic bf16 MFMA GEMM (128x128 tile) ----------------
using bf16x8 = __attribute__((ext_vector_type(8))) short;
using f32x4  = __attribute__((ext_vector_type(4))) float;

__global__ void __launch_bounds__(256) k_gemm_bf16(const unsigned short* Aq, const unsigned short* Bq,
                                                   const float* bias, float* C, int M, int N, int K, int obf){
  __shared__ unsigned short a_lds[128][40];
  __shared__ unsigned short b_lds[128][40];
  int ntiles = N >> 7;
  int bm = (blockIdx.x / ntiles) << 7;
  int bn = (blockIdx.x % ntiles) << 7;
  int tid = threadIdx.x;
  int wave = tid >> 6, lane = tid & 63;
  int wr = (wave >> 1) << 6, wc = (wave & 1) << 6;
  int la = lane & 15, lq = lane >> 4;
  f32x4 acc[4][4] = {};
  for (int k0 = 0; k0 < K; k0 += 32){
    {
      int r = tid >> 1, ch = (tid & 1) << 4;
      const uint4* asrc = (const uint4*)(Aq + (size_t)(bm + r)*K + k0 + ch);
      uint4 v0 = asrc[0], v1 = asrc[1];
      *(uint4*)&a_lds[r][ch]     = v0;
      *(uint4*)&a_lds[r][ch + 8] = v1;
      int kk = tid >> 3, n0 = (tid & 7) << 4;
      const unsigned short* bs = Bq + (size_t)(k0 + kk)*N + bn + n0;
      uint4 bv0 = *(const uint4*)bs, bv1 = *(const uint4*)(bs + 8);
      unsigned vals[8] = {bv0.x, bv0.y, bv0.z, bv0.w, bv1.x, bv1.y, bv1.z, bv1.w};
      #pragma unroll
      for (int i = 0; i < 8; i++){
        b_lds[n0 + 2*i][kk]     = (unsigned short)(vals[i] & 0xffffu);
        b_lds[n0 + 2*i + 1][kk] = (unsigned short)(vals[i] >> 16);
      }
    }
    __syncthreads();
    bf16x8 af[4], bfr[4];
    #pragma unroll
    for (int mt = 0; mt < 4; mt++) af[mt]  = *(const bf16x8*)&a_lds[wr + mt*16 + la][lq*8];
    #pragma unroll
    for (int nt = 0; nt < 4; nt++) bfr[nt] = *(const bf16x8*)&b_lds[wc + nt*16 + la][lq*8];
    #pragma unroll
    for (int mt = 0; mt < 4; mt++)
      #pragma unroll
      for (int nt = 0; nt < 4; nt++)
        acc[mt][nt] = __builtin_amdgcn_mfma_f32_16x16x32_bf16(af[mt], bfr[nt], acc[mt][nt], 0, 0, 0);
    __syncthreads();
  }
  #pragma unroll
  for (int mt = 0; mt < 4; mt++){
    int row0 = bm + wr + mt*16 + lq*4;
    #pragma unroll
    for (int nt = 0; nt < 4; nt++){
      int coln = bn + wc + nt*16 + la;
      float bb = bias ? bias[coln] : 0.f;
      #pragma unroll
      for (int r = 0; r < 4; r++){
        float v = acc[mt][nt][r] + bb;
        if (obf) ((unsigned short*)C)[(size_t)(row0 + r)*N + coln] = f2bf(v);
        else     C[(size_t)(row0 + r)*N + coln] = v;
      }
    }
  }
}

// ---------------- cooperative scan kernel ----------------

__device__ __forceinline__ void gsync(int* sc, int gen, int blk){
  __syncthreads();
  if (threadIdx.x == 0){
    __hip_atomic_fetch_add(&sc[(blk & 7)*64], 1, __ATOMIC_RELEASE, __HIP_MEMORY_SCOPE_AGENT);
    if (blk == 0){
      int total;
      do {
        total = 0;
        #pragma unroll
        for (int i = 0; i < 8; i++)
          total += __hip_atomic_load(&sc[i*64], __ATOMIC_ACQUIRE, __HIP_MEMORY_SCOPE_AGENT);
        if (total < gen*256) __builtin_amdgcn_s_sleep(1);
      } while (total < gen*256);
      __hip_atomic_store(&sc[512], gen, __ATOMIC_RELEASE, __HIP_MEMORY_SCOPE_AGENT);
    } else {
      while (__hip_atomic_load(&sc[512], __ATOMIC_ACQUIRE, __HIP_MEMORY_SCOPE_AGENT) < gen)
        __builtin_amdgcn_s_sleep(2);
    }
  }
  __syncthreads();
}

__global__ void __launch_bounds__(256, 1) k_loop(KParams p){
  const int tid = threadIdx.x, blk = blockIdx.x;
  const int wv = tid >> 6, lane = tid & 63;
  const int la = lane & 15, lq = lane >> 4;
  __shared__ unsigned short a_lds[32][520];          // S1: h tile; S4 reuses as [32][264]
  __shared__ float sm_att2[512], sm_fw[512], sm_e[224], sm_red[16], sm_alpha[224];
  __shared__ int sm_dl[32];
  int gen = 0;

  for (int t = 0; t <= T_; ++t){
    // ===== S1: MFMA  h @ Wt[n][k]  (att2|gate|ghh|fc), fc written straight to preds =====
    {
      int g, gmax;
      if (t == 0)      { g = blk;      gmax = 72;  }
      else if (t == T_){ g = 72 + blk; gmax = 229; }
      else             { g = blk;      gmax = 229; }
      if (g < gmax){
        if (tid < 32) sm_dl[tid] = p.declen[tid];
        {
          int row = tid >> 3, seg = tid & 7;
          const uint4* src = (const uint4*)(p.h_bf16 + row*512 + seg*64);
          uint4* dst = (uint4*)&a_lds[row][seg*64];
          #pragma unroll
          for (int i = 0; i < 8; i++) dst[i] = src[i];
        }
        __syncthreads();
        int n0 = g*64 + wv*16;
        if (n0 < N1){
          const unsigned short* wp = p.Wt + (size_t)(n0 + la)*512 + lq*8;
          bf16x8 bw[16];
          #pragma unroll
          for (int ks = 0; ks < 16; ks++) bw[ks] = *(const bf16x8*)(wp + ks*32);
          f32x4 ac0 = {}, ac1 = {};
          #pragma unroll
          for (int ks = 0; ks < 16; ks++){
            bf16x8 a0 = *(const bf16x8*)&a_lds[la][ks*32 + lq*8];
            bf16x8 a1 = *(const bf16x8*)&a_lds[16 + la][ks*32 + lq*8];
            ac0 = __builtin_amdgcn_mfma_f32_16x16x32_bf16(a0, bw[ks], ac0, 0, 0, 0);
            ac1 = __builtin_amdgcn_mfma_f32_16x16x32_bf16(a1, bw[ks], ac1, 0, 0, 0);
          }
          int col = n0 + la;
          if (col >= 4608){ // fc -> preds of step t-1 (only reached when t>=1)
            int v = col - 4608;
            float bb = p.fc_b[v];
            #pragma unroll
            for (int mt = 0; mt < 2; mt++){
              f32x4 ac = mt ? ac1 : ac0;
              #pragma unroll
              for (int r = 0; r < 4; r++){
                int b = mt*16 + lq*4 + r;
                bool act = (t - 1) < sm_dl[b];
                p.out_preds[((size_t)b*T_ + (t - 1))*V_ + v] = act ? (ac[r] + bb) : 0.f;
              }
            }
          } else {
            #pragma unroll
            for (int mt = 0; mt < 2; mt++){
              f32x4 ac = mt ? ac1 : ac0;
              #pragma unroll
              for (int r = 0; r < 4; r++){
                int b = mt*16 + lq*4 + r;
                p.s1out[b*4608 + col] = ac[r];
              }
            }
          }
        }
      }
    }
    if (t == T_) break;
    gsync(p.sync, ++gen, blk);
    // ===== S2 (blocks 0..31): e + softmax + alphas + awe (gated, bf16) =====
    if (blk < 32){
      int b = blk;
      for (int cc = tid; cc < 512; cc += 256){
        sm_att2[cc] = p.s1out[b*4608 + cc] + p.dec_att_b[cc];
        sm_fw[cc]   = p.full_att_w[cc];
      }
      __syncthreads();
      float a2[8], fwv[8];
      #pragma unroll
      for (int i = 0; i < 8; i++){ a2[i] = sm_att2[lane*8 + i]; fwv[i] = sm_fw[lane*8 + i]; }
      for (int pp = wv; pp < P_; pp += 4){
        uint4 u = *(const uint4*)(p.att1 + ((size_t)(b*P_ + pp))*512 + lane*8);
        float x[8];
        x[0]=bf2f(u.x&0xffffu); x[1]=bf2f(u.x>>16); x[2]=bf2f(u.y&0xffffu); x[3]=bf2f(u.y>>16);
        x[4]=bf2f(u.z&0xffffu); x[5]=bf2f(u.z>>16); x[6]=bf2f(u.w&0xffffu); x[7]=bf2f(u.w>>16);
        float s = 0.f;
        #pragma unroll
        for (int i = 0; i < 8; i++) s += fmaxf(x[i] + a2[i], 0.f)*fwv[i];
        #pragma unroll
        for (int off = 32; off; off >>= 1) s += __shfl_xor(s, off);
        if (lane == 0) sm_e[pp] = s;
      }
      __syncthreads();
      float v = (tid < P_) ? sm_e[tid] : -1e30f;
      #pragma unroll
      for (int off = 32; off; off >>= 1) v = fmaxf(v, __shfl_xor(v, off));
      if (lane == 0) sm_red[wv] = v;
      __syncthreads();
      float m = fmaxf(fmaxf(sm_red[0], sm_red[1]), fmaxf(sm_red[2], sm_red[3]));
      float ex = (tid < P_) ? __expf(sm_e[tid] - m) : 0.f;
      float sv = ex;
      #pragma unroll
      for (int off = 32; off; off >>= 1) sv += __shfl_xor(sv, off);
      if (lane == 0) sm_red[4 + wv] = sv;
      __syncthreads();
      float ssum = sm_red[4] + sm_red[5] + sm_red[6] + sm_red[7];
      if (tid < P_){
        float a = ex/ssum;
        sm_alpha[tid] = a;
        bool act = t < p.declen[b];
        p.out_alphas[((size_t)b*T_ + t)*P_ + tid] = act ? a : 0.f;
      }
      __syncthreads();
      // awe = gate * (alpha @ enc), 8 cols/thread
      int d0 = tid*8;
      const unsigned short* eb = p.enc_bf16 + (size_t)b*P_*D_ + d0;
      float aw[8] = {0.f,0.f,0.f,0.f,0.f,0.f,0.f,0.f};
      for (int pp = 0; pp < P_; ++pp){
        uint4 u = *(const uint4*)(eb + (size_t)pp*D_);
        float al = sm_alpha[pp];
        aw[0] += al*bf2f(u.x&0xffffu); aw[1] += al*bf2f(u.x>>16);
        aw[2] += al*bf2f(u.y&0xffffu); aw[3] += al*bf2f(u.y>>16);
        aw[4] += al*bf2f(u.z&0xffffu); aw[5] += al*bf2f(u.z>>16);
        aw[6] += al*bf2f(u.w&0xffffu); aw[7] += al*bf2f(u.w>>16);
      }
      float4 q1 = *(const float4*)(p.s1out + b*4608 + 512 + d0);
      float4 q2 = *(const float4*)(p.s1out + b*4608 + 512 + d0 + 4);
      float4 b1 = *(const float4*)(p.f_beta_b + d0);
      float4 b2 = *(const float4*)(p.f_beta_b + d0 + 4);
      float gt[8] = { sigm(q1.x+b1.x), sigm(q1.y+b1.y), sigm(q1.z+b1.z), sigm(q1.w+b1.w),
                      sigm(q2.x+b2.x), sigm(q2.y+b2.y), sigm(q2.z+b2.z), sigm(q2.w+b2.w) };
      uint4 outp;
      outp.x = pack2(aw[0]*gt[0], aw[1]*gt[1]);
      outp.y = pack2(aw[2]*gt[2], aw[3]*gt[3]);
      outp.z = pack2(aw[4]*gt[4], aw[5]*gt[5]);
      outp.w = pack2(aw[6]*gt[6], aw[7]*gt[7]);
      *(uint4*)(p.awe_bf16 + b*2048 + d0) = outp;
    }
    gsync(p.sync, ++gen, blk);
    // ===== S4: MFMA  awe @ Wt2[n][k], K-split 8 =====
    {
      int ng = blk & 31, kh = blk >> 5;
      unsigned short (*a4)[264] = (unsigned short (*)[264])&a_lds[0][0];
      {
        int r = tid >> 3, c0 = (tid & 7)*32;
        const uint4* s = (const uint4*)(p.awe_bf16 + r*2048 + kh*256 + c0);
        uint4* d = (uint4*)&a4[r][c0];
        #pragma unroll
        for (int i = 0; i < 4; i++) d[i] = s[i];
      }
      __syncthreads();
      int n0 = ng*64 + wv*16;
      const unsigned short* wp = p.Wt2 + (size_t)(n0 + la)*2048 + kh*256 + lq*8;
      bf16x8 bw[8];
      #pragma unroll
      for (int ks = 0; ks < 8; ks++) bw[ks] = *(const bf16x8*)(wp + ks*32);
      f32x4 ac0 = {}, ac1 = {};
      #pragma unroll
      for (int ks = 0; ks < 8; ks++){
        bf16x8 a0 = *(const bf16x8*)&a4[la][ks*32 + lq*8];
        bf16x8 a1 = *(const bf16x8*)&a4[16 + la][ks*32 + lq*8];
        ac0 = __builtin_amdgcn_mfma_f32_16x16x32_bf16(a0, bw[ks], ac0, 0, 0, 0);
        ac1 = __builtin_amdgcn_mfma_f32_16x16x32_bf16(a1, bw[ks], ac1, 0, 0, 0);
      }
      #pragma unroll
      for (int mt = 0; mt < 2; mt++){
        f32x4 ac = mt ? ac1 : ac0;
        #pragma unroll
        for (int r = 0; r < 4; r++){
          int b = mt*16 + lq*4 + r;
          p.gpart[((size_t)(kh*32 + b))*2048 + n0 + la] = ac[r];
        }
      }
    }
    gsync(p.sync, ++gen, blk);
    // ===== S5: reduce partials + LSTM cell =====
    if (blk < 64){
      int b = blk >> 1, j = (blk & 1)*256 + tid;
      float gq[4];
      #pragma unroll
      for (int q = 0; q < 4; q++){
        int col = q*512 + j;
        float s = p.gpre[((size_t)t*32 + b)*2048 + col] + p.s1out[b*4608 + 2560 + col];
        #pragma unroll
        for (int kh = 0; kh < 8; kh++) s += p.gpart[((size_t)(kh*32 + b))*2048 + col];
        gq[q] = s;
      }
      float cold = p.c[b*512 + j];
      float cn = sigm(gq[1])*cold + sigm(gq[0])*tanh_f(gq[2]);
      float hn = sigm(gq[3])*tanh_f(cn);
      if (t < p.declen[b]){
        p.c[b*512 + j] = cn;
        p.h_bf16[b*512 + j] = f2bf(hn);
      }
    }
    gsync(p.sync, ++gen, blk);
  }
}

// ---------------- host launcher ----------------

extern "C" void kernel_launch(void* const* d_in, const int* in_sizes, int n_in,
                              void* d_out, int out_size, void* d_ws, size_t ws_size,
                              hipStream_t stream){
  (void)in_sizes; (void)n_in; (void)out_size; (void)ws_size;
  KParams p;
  p.encoder_out = (const float*)d_in[0];
  p.captions    = (const int*)d_in[1];
  p.cap_lens    = (const int*)d_in[2];
  p.enc_att_w   = (const float*)d_in[3];  p.enc_att_b = (const float*)d_in[4];
  p.dec_att_w   = (const float*)d_in[5];  p.dec_att_b = (const float*)d_in[6];
  p.full_att_w  = (const float*)d_in[7];  p.full_att_b = (const float*)d_in[8];
  p.emb         = (const float*)d_in[9];
  p.init_h_w    = (const float*)d_in[10]; p.init_h_b = (const float*)d_in[11];
  p.init_c_w    = (const float*)d_in[12]; p.init_c_b = (const float*)d_in[13];
  p.f_beta_w    = (const float*)d_in[14]; p.f_beta_b = (const float*)d_in[15];
  p.lstm_w_ih   = (const float*)d_in[16]; p.lstm_w_hh = (const float*)d_in[17]; p.lstm_b = (const float*)d_in[18];
  p.fc_w        = (const float*)d_in[19]; p.fc_b = (const float*)d_in[20];

  float* out = (float*)d_out;
  p.out_preds   = out;                       // 6,400,000
  p.out_caps    = out + 6400000;             // 672
  p.out_declens = out + 6400672;             // 32
  p.out_alphas  = out + 6400704;             // 125,440
  p.out_sortind = out + 6526144;             // 32

  char* w = (char*)d_ws; size_t off = 0;
  auto alloc = [&](size_t bytes)->char*{ char* r = w + off; off = (off + bytes + 255) & ~(size_t)255; return r; };
  p.sort_ind  = (int*)alloc(128);
  p.declen    = (int*)alloc(128);
  p.caps_s    = (int*)alloc(2688);
  p.h_bf16    = (unsigned short*)alloc(32768);
  p.c         = (float*)alloc(65536);
  p.mean      = (float*)alloc(262144);
  p.enc_bf16  = (unsigned short*)alloc(25690112);
  p.waw_bf16  = (unsigned short*)alloc(2097152);
  p.wihE_bf16 = (unsigned short*)alloc(2097152);
  p.embs_bf16 = (unsigned short*)alloc(655360);
  p.att1      = (unsigned short*)alloc(6422528);   // [6272][512] bf16
  p.Wt        = (unsigned short*)alloc(14958592);  // [14608][512] bf16 (transposed weights)
  p.Wt2       = (unsigned short*)alloc(8388608);   // [2048][2048] bf16 (transposed w_ih awe part)
  p.gpre      = (float*)alloc(5242880);
  p.s1out     = (float*)alloc(589824);             // [32][4608]
  p.awe_bf16  = (unsigned short*)alloc(131072);
  p.gpart     = (float*)alloc(2097152);            // 8 x [32][2048]
  p.sync      = (int*)alloc(4096);
  p.h0part    = (float*)p.gpart;                   // aliased: prologue-only

  hipMemsetAsync(p.sync, 0, 4096, stream);
  hipLaunchKernelGGL(k_meta,    dim3(1),     dim3(64),  0, stream, p);
  hipLaunchKernelGGL(k_encbf,   dim3(12544), dim3(256), 0, stream, p);
  hipLaunchKernelGGL(k_wbf,     dim3(2048),  dim3(256), 0, stream, p);
  // transposed bf16 weights for the scan loop
  hipLaunchKernelGGL(k_transpose, dim3(16*16),  dim3(256), 0, stream, p.dec_att_w, p.Wt,              512, 512);
  hipLaunchKernelGGL(k_transpose, dim3(16*64),  dim3(256), 0, stream, p.f_beta_w,  p.Wt + 512*512,    512, 2048);
  hipLaunchKernelGGL(k_transpose, dim3(16*64),  dim3(256), 0, stream, p.lstm_w_hh, p.Wt + 2560*512,   512, 2048);
  hipLaunchKernelGGL(k_transpose, dim3(16*313), dim3(256), 0, stream, p.fc_w,      p.Wt + 4608*512,   512, 10000);
  hipLaunchKernelGGL(k_transpose, dim3(64*64),  dim3(256), 0, stream, p.lstm_w_ih + 512*2048, p.Wt2, 2048, 2048);
  hipLaunchKernelGGL(k_mean,    dim3(128),   dim3(256), 0, stream, p);
  hipLaunchKernelGGL(k_h0c0,    dim3(64),    dim3(256), 0, stream, p);
  hipLaunchKernelGGL(k_h0c0red, dim3(128),   dim3(256), 0, stream, p);
  hipLaunchKernelGGL(k_embs,    dim3(320),   dim3(256), 0, stream, p);
  hipLaunchKernelGGL(k_gemm_bf16, dim3(80),  dim3(256), 0, stream,
                     (const unsigned short*)p.embs_bf16, (const unsigned short*)p.wihE_bf16,
                     p.lstm_b, p.gpre, 640, 2048, 512, 0);
  hipLaunchKernelGGL(k_gemm_bf16, dim3(196), dim3(256), 0, stream,
                     (const unsigned short*)p.enc_bf16, (const unsigned short*)p.waw_bf16,
                     p.enc_att_b, (float*)p.att1, 6272, 512, 2048, 1);

  void* args[] = { (void*)&p };
  hipLaunchCooperativeKernel((void*)k_loop, dim3(256), dim3(256), args, 0, stream);
}

// Round 3
// 2276.689 us; speedup vs baseline: 2.8535x; 2.8535x over previous
//
#include <hip/hip_runtime.h>

#define B_ 32
#define P_ 196
#define D_ 2048
#define A_ 512
#define E_ 512
#define H_ 512
#define V_ 10000
#define L_ 21
#define T_ 20
#define N1 14608            /* 512 att2 + 2048 gate + 2048 ghh + 10000 fc */

struct KParams {
  const float* encoder_out; const int* captions; const int* cap_lens;
  const float* enc_att_w; const float* enc_att_b;
  const float* dec_att_w; const float* dec_att_b;
  const float* full_att_w; const float* full_att_b;
  const float* emb;
  const float* init_h_w; const float* init_h_b;
  const float* init_c_w; const float* init_c_b;
  const float* f_beta_w; const float* f_beta_b;
  const float* lstm_w_ih; const float* lstm_w_hh; const float* lstm_b;
  const float* fc_w; const float* fc_b;
  float* out_preds; float* out_caps; float* out_declens; float* out_alphas; float* out_sortind;
  int* sort_ind; int* declen; int* caps_s;
  unsigned short* h_bf16; float* c; float* mean; float* h0part;
  unsigned short* enc_bf16; unsigned short* waw_bf16; unsigned short* wihE_bf16; unsigned short* embs_bf16;
  unsigned short* att1; unsigned short* Wt; unsigned short* Wt2; unsigned short* awe_bf16;
  float* gpre; float* s1out; float* gpart;
  int* sync;
};

__device__ __forceinline__ unsigned short f2bf(float x){
  unsigned u = __float_as_uint(x);
  unsigned r = ((u >> 16) & 1u) + 0x7FFFu;
  return (unsigned short)((u + r) >> 16);
}
__device__ __forceinline__ unsigned pack2(float a, float b){
  return (unsigned)f2bf(a) | ((unsigned)f2bf(b) << 16);
}
__device__ __forceinline__ float bf2f(unsigned u16){ return __uint_as_float(u16 << 16); }
__device__ __forceinline__ float sigm(float x){ return 1.f/(1.f + __expf(-x)); }
__device__ __forceinline__ float tanh_f(float x){ return 1.f - 2.f/(__expf(2.f*x) + 1.f); }

// ---------------- prologue kernels ----------------

__global__ void k_meta(KParams p){
  __shared__ int len[32], sidx[32], sdecl[32];
  int tid = threadIdx.x;
  if (tid < 32) len[tid] = p.cap_lens[tid];
  __syncthreads();
  if (tid == 0){
    bool used[32];
    for (int i = 0; i < 32; i++) used[i] = false;
    for (int r = 0; r < 32; r++){
      int best = -1, bl = -2;
      for (int i = 0; i < 32; i++) if (!used[i] && len[i] > bl){ bl = len[i]; best = i; }
      used[best] = true; sidx[r] = best; sdecl[r] = bl - 1;
    }
  }
  __syncthreads();
  if (tid < 32){
    p.sort_ind[tid] = sidx[tid]; p.out_sortind[tid] = (float)sidx[tid];
    p.declen[tid]   = sdecl[tid]; p.out_declens[tid] = (float)sdecl[tid];
  }
  for (int idx = tid; idx < B_*L_; idx += 64){
    int b = idx / L_, l = idx - b*L_;
    int cv = p.captions[sidx[b]*L_ + l];
    p.caps_s[idx] = cv; p.out_caps[idx] = (float)cv;
  }
}

__global__ void k_encbf(KParams p){ // sorted encoder -> bf16
  int q = blockIdx.x*256 + threadIdx.x;
  const int QB = P_*D_/4;
  int b = q / QB; int r = q - b*QB;
  float4 v = ((const float4*)(p.encoder_out + (size_t)p.sort_ind[b]*(P_*D_)))[r];
  ((uint2*)p.enc_bf16)[q] = make_uint2(pack2(v.x, v.y), pack2(v.z, v.w));
}

__global__ void k_wbf(KParams p){ // enc_att_w and lstm_w_ih[:512] -> bf16
  int q = blockIdx.x*256 + threadIdx.x; // 524288 quads
  const float4* src; uint2* dst; int qq;
  if (q < 262144){ src = (const float4*)p.enc_att_w; dst = (uint2*)p.waw_bf16;  qq = q; }
  else           { src = (const float4*)p.lstm_w_ih; dst = (uint2*)p.wihE_bf16; qq = q - 262144; }
  float4 v = src[qq];
  dst[qq] = make_uint2(pack2(v.x, v.y), pack2(v.z, v.w));
}

// transpose fp32 [R][C] -> bf16 [C][R]
__global__ void k_transpose(const float* src, unsigned short* dst, int R, int C){
  __shared__ float tl[32][33];
  int tilesC = (C + 31) >> 5;
  int tr = blockIdx.x / tilesC, tc = blockIdx.x - tr*tilesC;
  int r0 = tr << 5, c0 = tc << 5;
  int tid = threadIdx.x;
  int r = tid >> 3, cs = (tid & 7) << 2;
  #pragma unroll
  for (int i = 0; i < 4; i++){
    int c = c0 + cs + i;
    tl[r][cs + i] = (c < C) ? src[(size_t)(r0 + r)*C + c] : 0.f;
  }
  __syncthreads();
  int c = tid >> 3, rs = (tid & 7) << 2;
  if (c0 + c < C){
    unsigned lo = pack2(tl[rs][c], tl[rs+1][c]);
    unsigned hi = pack2(tl[rs+2][c], tl[rs+3][c]);
    *(uint2*)(dst + (size_t)(c0 + c)*R + r0 + rs) = make_uint2(lo, hi);
  }
}

__global__ void k_mean(KParams p){
  int idx = blockIdx.x*256 + threadIdx.x; // 32768
  int b = idx >> 10, d2 = idx & 1023;
  const unsigned short* e = p.enc_bf16 + (size_t)b*P_*D_ + d2*2;
  float s0 = 0.f, s1 = 0.f;
  for (int pp = 0; pp < P_; ++pp){
    unsigned u = *(const unsigned*)(e + (size_t)pp*D_);
    s0 += bf2f(u & 0xffffu); s1 += bf2f(u >> 16);
  }
  const float inv = 1.f/196.f;
  p.mean[b*D_ + d2*2]     = s0*inv;
  p.mean[b*D_ + d2*2 + 1] = s1*inv;
}

__global__ void k_h0c0(KParams p){
  __shared__ float mlds[32*128];
  int tid = threadIdx.x;
  int tile = blockIdx.x & 3, kp = blockIdx.x >> 2;
  int k0 = kp*128;
  {
    int tb = tid >> 3, ti = tid & 7;
    const float4* src = (const float4*)(p.mean + tb*D_ + k0);
    float4* dst = (float4*)(mlds + tb*128);
    #pragma unroll
    for (int i = 0; i < 4; i++) dst[ti + 8*i] = src[ti + 8*i];
  }
  __syncthreads();
  int col = tile*256 + tid;
  const float* wb = (col < 512 ? p.init_h_w + col : p.init_c_w + (col - 512)) + (size_t)k0*H_;
  float acc[32];
  #pragma unroll
  for (int i = 0; i < 32; i++) acc[i] = 0.f;
  for (int k = 0; k < 128; k += 4){
    float w0 = wb[0], w1 = wb[H_], w2 = wb[2*H_], w3 = wb[3*H_];
    wb += 4*H_;
    #pragma unroll
    for (int i = 0; i < 32; i++){
      float4 hv = *(const float4*)(mlds + i*128 + k);
      acc[i] += hv.x*w0 + hv.y*w1 + hv.z*w2 + hv.w*w3;
    }
  }
  float* op = p.h0part + (size_t)kp*32768 + col;
  #pragma unroll
  for (int i = 0; i < 32; i++) op[i*1024] = acc[i];
}

__global__ void k_h0c0red(KParams p){
  int idx = blockIdx.x*256 + threadIdx.x; // 32768
  int b = idx >> 10, col = idx & 1023;
  float s = 0.f;
  #pragma unroll
  for (int kp = 0; kp < 16; kp++) s += p.h0part[(size_t)kp*32768 + b*1024 + col];
  if (col < 512) p.h_bf16[b*512 + col] = f2bf(s + p.init_h_b[col]);
  else           p.c[b*512 + col - 512] = s + p.init_c_b[col - 512];
}

__global__ void k_embs(KParams p){
  int q = blockIdx.x*256 + threadIdx.x; // 81920 quads
  int row = q >> 7, qi = q & 127;
  int t = row >> 5, b = row & 31;
  int cap = p.caps_s[b*L_ + t];
  float4 v = ((const float4*)(p.emb + (size_t)cap*E_))[qi];
  ((uint2*)p.embs_bf16)[q] = make_uint2(pack2(v.x, v.y), pack2(v.z, v.w));
}

// ---------------- generic bf16 MFMA GEMM (128x128 tile) ----------------
using bf16x8 = __attribute__((ext_vector_type(8))) short;
using f32x4  = __attribute__((ext_vector_type(4))) float;

__global__ void __launch_bounds__(256) k_gemm_bf16(const unsigned short* Aq, const unsigned short* Bq,
                                                   const float* bias, float* C, int M, int N, int K, int obf){
  __shared__ unsigned short a_lds[128][40];
  __shared__ unsigned short b_lds[128][40];
  int ntiles = N >> 7;
  int bm = (blockIdx.x / ntiles) << 7;
  int bn = (blockIdx.x % ntiles) << 7;
  int tid = threadIdx.x;
  int wave = tid >> 6, lane = tid & 63;
  int wr = (wave >> 1) << 6, wc = (wave & 1) << 6;
  int la = lane & 15, lq = lane >> 4;
  f32x4 acc[4][4] = {};
  for (int k0 = 0; k0 < K; k0 += 32){
    {
      int r = tid >> 1, ch = (tid & 1) << 4;
      const uint4* asrc = (const uint4*)(Aq + (size_t)(bm + r)*K + k0 + ch);
      uint4 v0 = asrc[0], v1 = asrc[1];
      *(uint4*)&a_lds[r][ch]     = v0;
      *(uint4*)&a_lds[r][ch + 8] = v1;
      int kk = tid >> 3, n0 = (tid & 7) << 4;
      const unsigned short* bs = Bq + (size_t)(k0 + kk)*N + bn + n0;
      uint4 bv0 = *(const uint4*)bs, bv1 = *(const uint4*)(bs + 8);
      unsigned vals[8] = {bv0.x, bv0.y, bv0.z, bv0.w, bv1.x, bv1.y, bv1.z, bv1.w};
      #pragma unroll
      for (int i = 0; i < 8; i++){
        b_lds[n0 + 2*i][kk]     = (unsigned short)(vals[i] & 0xffffu);
        b_lds[n0 + 2*i + 1][kk] = (unsigned short)(vals[i] >> 16);
      }
    }
    __syncthreads();
    bf16x8 af[4], bfr[4];
    #pragma unroll
    for (int mt = 0; mt < 4; mt++) af[mt]  = *(const bf16x8*)&a_lds[wr + mt*16 + la][lq*8];
    #pragma unroll
    for (int nt = 0; nt < 4; nt++) bfr[nt] = *(const bf16x8*)&b_lds[wc + nt*16 + la][lq*8];
    #pragma unroll
    for (int mt = 0; mt < 4; mt++)
      #pragma unroll
      for (int nt = 0; nt < 4; nt++)
        acc[mt][nt] = __builtin_amdgcn_mfma_f32_16x16x32_bf16(af[mt], bfr[nt], acc[mt][nt], 0, 0, 0);
    __syncthreads();
  }
  #pragma unroll
  for (int mt = 0; mt < 4; mt++){
    int row0 = bm + wr + mt*16 + lq*4;
    #pragma unroll
    for (int nt = 0; nt < 4; nt++){
      int coln = bn + wc + nt*16 + la;
      float bb = bias ? bias[coln] : 0.f;
      #pragma unroll
      for (int r = 0; r < 4; r++){
        float v = acc[mt][nt][r] + bb;
        if (obf) ((unsigned short*)C)[(size_t)(row0 + r)*N + coln] = f2bf(v);
        else     C[(size_t)(row0 + r)*N + coln] = v;
      }
    }
  }
}

// ---------------- cooperative scan kernel ----------------
// Spread-line barrier: 32 arrival-counter lines (64B apart), 64 flag lines.
// Relaxed polls + acquire/release fences avoid both same-line contention and
// per-load acquire serialization.

__device__ __forceinline__ void gsync(int* sc, int gen, int blk){
  __syncthreads();
  if (threadIdx.x == 0){
    __hip_atomic_fetch_add(&sc[(blk & 31)*16], 1, __ATOMIC_RELEASE, __HIP_MEMORY_SCOPE_AGENT);
    if (blk == 0){
      int total;
      do {
        total = 0;
        #pragma unroll
        for (int i = 0; i < 32; i++)
          total += __hip_atomic_load(&sc[i*16], __ATOMIC_RELAXED, __HIP_MEMORY_SCOPE_AGENT);
        if (total < gen*256) __builtin_amdgcn_s_sleep(1);
      } while (total < gen*256);
      __builtin_amdgcn_fence(__ATOMIC_ACQ_REL, "agent");
      #pragma unroll
      for (int i = 0; i < 64; i++)
        __hip_atomic_store(&sc[512 + i*16], gen, __ATOMIC_RELAXED, __HIP_MEMORY_SCOPE_AGENT);
    } else {
      while (__hip_atomic_load(&sc[512 + (blk >> 2)*16], __ATOMIC_RELAXED, __HIP_MEMORY_SCOPE_AGENT) < gen)
        __builtin_amdgcn_s_sleep(2);
      __builtin_amdgcn_fence(__ATOMIC_ACQUIRE, "agent");
    }
  }
  __syncthreads();
}

__device__ __forceinline__ void stage_h(const KParams& p, unsigned short (*a_lds)[520], int tid){
  int row = tid >> 3, seg = tid & 7;
  const uint4* src = (const uint4*)(p.h_bf16 + row*512 + seg*64);
  uint4* dst = (uint4*)&a_lds[row][seg*64];
  #pragma unroll
  for (int i = 0; i < 8; i++) dst[i] = src[i];
}

__device__ __forceinline__ void fc_stage(const KParams& p, unsigned short (*a_lds)[520],
                                         const int* sm_dl, int g, int wv, int la, int lq, int tpred){
  int n0g = g*64 + wv*16;
  const unsigned short* wp = p.Wt + (size_t)(4608 + n0g + la)*512 + lq*8;
  bf16x8 bw[16];
  #pragma unroll
  for (int ks = 0; ks < 16; ks++) bw[ks] = *(const bf16x8*)(wp + ks*32);
  f32x4 ac0 = {}, ac1 = {};
  #pragma unroll
  for (int ks = 0; ks < 16; ks++){
    bf16x8 a0 = *(const bf16x8*)&a_lds[la][ks*32 + lq*8];
    bf16x8 a1 = *(const bf16x8*)&a_lds[16 + la][ks*32 + lq*8];
    ac0 = __builtin_amdgcn_mfma_f32_16x16x32_bf16(a0, bw[ks], ac0, 0, 0, 0);
    ac1 = __builtin_amdgcn_mfma_f32_16x16x32_bf16(a1, bw[ks], ac1, 0, 0, 0);
  }
  int v = n0g + la;
  if (v < V_){
    float bb = p.fc_b[v];
    #pragma unroll
    for (int mt = 0; mt < 2; mt++){
      f32x4 ac = mt ? ac1 : ac0;
      #pragma unroll
      for (int r = 0; r < 4; r++){
        int b = mt*16 + lq*4 + r;
        bool act = tpred < sm_dl[b];
        p.out_preds[((size_t)b*T_ + tpred)*V_ + v] = act ? (ac[r] + bb) : 0.f;
      }
    }
  }
}

__global__ void __launch_bounds__(256, 1) k_loop(KParams p){
  const int tid = threadIdx.x, blk = blockIdx.x;
  const int wv = tid >> 6, lane = tid & 63;
  const int la = lane & 15, lq = lane >> 4;
  __shared__ unsigned short a_lds[32][520];          // h tile (S1/fc); S4 reuses as [32][264]
  __shared__ float sm_att2[512], sm_fw[512], sm_e[224], sm_red[16], sm_alpha[224];
  __shared__ int sm_dl[32];
  int gen = 0;

  for (int t = 0; t < T_; ++t){
    // ===== S1: MFMA h @ Wt (att2|gate|ghh only, 72 groups) =====
    if (blk < 72){
      stage_h(p, a_lds, tid);
      __syncthreads();
      int n0 = blk*64 + wv*16;
      const unsigned short* wp = p.Wt + (size_t)(n0 + la)*512 + lq*8;
      bf16x8 bw[16];
      #pragma unroll
      for (int ks = 0; ks < 16; ks++) bw[ks] = *(const bf16x8*)(wp + ks*32);
      f32x4 ac0 = {}, ac1 = {};
      #pragma unroll
      for (int ks = 0; ks < 16; ks++){
        bf16x8 a0 = *(const bf16x8*)&a_lds[la][ks*32 + lq*8];
        bf16x8 a1 = *(const bf16x8*)&a_lds[16 + la][ks*32 + lq*8];
        ac0 = __builtin_amdgcn_mfma_f32_16x16x32_bf16(a0, bw[ks], ac0, 0, 0, 0);
        ac1 = __builtin_amdgcn_mfma_f32_16x16x32_bf16(a1, bw[ks], ac1, 0, 0, 0);
      }
      int col = n0 + la;
      #pragma unroll
      for (int mt = 0; mt < 2; mt++){
        f32x4 ac = mt ? ac1 : ac0;
        #pragma unroll
        for (int r = 0; r < 4; r++){
          int b = mt*16 + lq*4 + r;
          p.s1out[b*4608 + col] = ac[r];
        }
      }
    }
    gsync(p.sync, ++gen, blk);
    // ===== S2 window: blocks 0..31 attention | blocks 32..188 fc(preds[t-1]) =====
    if (blk < 32){
      int b = blk;
      for (int cc = tid; cc < 512; cc += 256){
        sm_att2[cc] = p.s1out[b*4608 + cc] + p.dec_att_b[cc];
        sm_fw[cc]   = p.full_att_w[cc];
      }
      __syncthreads();
      float a2[8], fwv[8];
      #pragma unroll
      for (int i = 0; i < 8; i++){ a2[i] = sm_att2[lane*8 + i]; fwv[i] = sm_fw[lane*8 + i]; }
      for (int pp = wv; pp < P_; pp += 4){
        uint4 u = *(const uint4*)(p.att1 + ((size_t)(b*P_ + pp))*512 + lane*8);
        float x[8];
        x[0]=bf2f(u.x&0xffffu); x[1]=bf2f(u.x>>16); x[2]=bf2f(u.y&0xffffu); x[3]=bf2f(u.y>>16);
        x[4]=bf2f(u.z&0xffffu); x[5]=bf2f(u.z>>16); x[6]=bf2f(u.w&0xffffu); x[7]=bf2f(u.w>>16);
        float s = 0.f;
        #pragma unroll
        for (int i = 0; i < 8; i++) s += fmaxf(x[i] + a2[i], 0.f)*fwv[i];
        #pragma unroll
        for (int off = 32; off; off >>= 1) s += __shfl_xor(s, off);
        if (lane == 0) sm_e[pp] = s;
      }
      __syncthreads();
      float v = (tid < P_) ? sm_e[tid] : -1e30f;
      #pragma unroll
      for (int off = 32; off; off >>= 1) v = fmaxf(v, __shfl_xor(v, off));
      if (lane == 0) sm_red[wv] = v;
      __syncthreads();
      float m = fmaxf(fmaxf(sm_red[0], sm_red[1]), fmaxf(sm_red[2], sm_red[3]));
      float ex = (tid < P_) ? __expf(sm_e[tid] - m) : 0.f;
      float sv = ex;
      #pragma unroll
      for (int off = 32; off; off >>= 1) sv += __shfl_xor(sv, off);
      if (lane == 0) sm_red[4 + wv] = sv;
      __syncthreads();
      float ssum = sm_red[4] + sm_red[5] + sm_red[6] + sm_red[7];
      if (tid < P_){
        float a = ex/ssum;
        sm_alpha[tid] = a;
        bool act = t < p.declen[b];
        p.out_alphas[((size_t)b*T_ + t)*P_ + tid] = act ? a : 0.f;
      }
      __syncthreads();
      // awe = gate * (alpha @ enc): 4 interleaved row streams for load concurrency
      int d0 = tid*8;
      const unsigned short* eb = p.enc_bf16 + (size_t)b*P_*D_ + d0;
      float aw[8] = {0.f,0.f,0.f,0.f,0.f,0.f,0.f,0.f};
      for (int pp = 0; pp < 49; ++pp){
        uint4 u0 = *(const uint4*)(eb + (size_t)(pp      )*D_);
        uint4 u1 = *(const uint4*)(eb + (size_t)(pp +  49)*D_);
        uint4 u2 = *(const uint4*)(eb + (size_t)(pp +  98)*D_);
        uint4 u3 = *(const uint4*)(eb + (size_t)(pp + 147)*D_);
        float al0 = sm_alpha[pp], al1 = sm_alpha[pp+49], al2 = sm_alpha[pp+98], al3 = sm_alpha[pp+147];
        aw[0] += al0*bf2f(u0.x&0xffffu) + al1*bf2f(u1.x&0xffffu) + al2*bf2f(u2.x&0xffffu) + al3*bf2f(u3.x&0xffffu);
        aw[1] += al0*bf2f(u0.x>>16)     + al1*bf2f(u1.x>>16)     + al2*bf2f(u2.x>>16)     + al3*bf2f(u3.x>>16);
        aw[2] += al0*bf2f(u0.y&0xffffu) + al1*bf2f(u1.y&0xffffu) + al2*bf2f(u2.y&0xffffu) + al3*bf2f(u3.y&0xffffu);
        aw[3] += al0*bf2f(u0.y>>16)     + al1*bf2f(u1.y>>16)     + al2*bf2f(u2.y>>16)     + al3*bf2f(u3.y>>16);
        aw[4] += al0*bf2f(u0.z&0xffffu) + al1*bf2f(u1.z&0xffffu) + al2*bf2f(u2.z&0xffffu) + al3*bf2f(u3.z&0xffffu);
        aw[5] += al0*bf2f(u0.z>>16)     + al1*bf2f(u1.z>>16)     + al2*bf2f(u2.z>>16)     + al3*bf2f(u3.z>>16);
        aw[6] += al0*bf2f(u0.w&0xffffu) + al1*bf2f(u1.w&0xffffu) + al2*bf2f(u2.w&0xffffu) + al3*bf2f(u3.w&0xffffu);
        aw[7] += al0*bf2f(u0.w>>16)     + al1*bf2f(u1.w>>16)     + al2*bf2f(u2.w>>16)     + al3*bf2f(u3.w>>16);
      }
      float4 q1 = *(const float4*)(p.s1out + b*4608 + 512 + d0);
      float4 q2 = *(const float4*)(p.s1out + b*4608 + 512 + d0 + 4);
      float4 b1 = *(const float4*)(p.f_beta_b + d0);
      float4 b2 = *(const float4*)(p.f_beta_b + d0 + 4);
      float gt[8] = { sigm(q1.x+b1.x), sigm(q1.y+b1.y), sigm(q1.z+b1.z), sigm(q1.w+b1.w),
                      sigm(q2.x+b2.x), sigm(q2.y+b2.y), sigm(q2.z+b2.z), sigm(q2.w+b2.w) };
      uint4 outp;
      outp.x = pack2(aw[0]*gt[0], aw[1]*gt[1]);
      outp.y = pack2(aw[2]*gt[2], aw[3]*gt[3]);
      outp.z = pack2(aw[4]*gt[4], aw[5]*gt[5]);
      outp.w = pack2(aw[6]*gt[6], aw[7]*gt[7]);
      *(uint4*)(p.awe_bf16 + b*2048 + d0) = outp;
    } else if (blk < 189 && t > 0){
      if (tid < 32) sm_dl[tid] = p.declen[tid];
      stage_h(p, a_lds, tid);
      __syncthreads();
      fc_stage(p, a_lds, sm_dl, blk - 32, wv, la, lq, t - 1);
    }
    gsync(p.sync, ++gen, blk);
    // ===== S4: MFMA awe @ Wt2, K-split 8 (all 256 blocks) =====
    {
      int ng = blk & 31, kh = blk >> 5;
      unsigned short (*a4)[264] = (unsigned short (*)[264])&a_lds[0][0];
      {
        int r = tid >> 3, c0 = (tid & 7)*32;
        const uint4* s = (const uint4*)(p.awe_bf16 + r*2048 + kh*256 + c0);
        uint4* d = (uint4*)&a4[r][c0];
        #pragma unroll
        for (int i = 0; i < 4; i++) d[i] = s[i];
      }
      __syncthreads();
      int n0 = ng*64 + wv*16;
      const unsigned short* wp = p.Wt2 + (size_t)(n0 + la)*2048 + kh*256 + lq*8;
      bf16x8 bw[8];
      #pragma unroll
      for (int ks = 0; ks < 8; ks++) bw[ks] = *(const bf16x8*)(wp + ks*32);
      f32x4 ac0 = {}, ac1 = {};
      #pragma unroll
      for (int ks = 0; ks < 8; ks++){
        bf16x8 a0 = *(const bf16x8*)&a4[la][ks*32 + lq*8];
        bf16x8 a1 = *(const bf16x8*)&a4[16 + la][ks*32 + lq*8];
        ac0 = __builtin_amdgcn_mfma_f32_16x16x32_bf16(a0, bw[ks], ac0, 0, 0, 0);
        ac1 = __builtin_amdgcn_mfma_f32_16x16x32_bf16(a1, bw[ks], ac1, 0, 0, 0);
      }
      #pragma unroll
      for (int mt = 0; mt < 2; mt++){
        f32x4 ac = mt ? ac1 : ac0;
        #pragma unroll
        for (int r = 0; r < 4; r++){
          int b = mt*16 + lq*4 + r;
          p.gpart[((size_t)(kh*32 + b))*2048 + n0 + la] = ac[r];
        }
      }
    }
    gsync(p.sync, ++gen, blk);
    // ===== S5: reduce partials + LSTM cell =====
    if (blk < 64){
      int b = blk >> 1, j = (blk & 1)*256 + tid;
      float gq[4];
      #pragma unroll
      for (int q = 0; q < 4; q++){
        int col = q*512 + j;
        float s = p.gpre[((size_t)t*32 + b)*2048 + col] + p.s1out[b*4608 + 2560 + col];
        #pragma unroll
        for (int kh = 0; kh < 8; kh++) s += p.gpart[((size_t)(kh*32 + b))*2048 + col];
        gq[q] = s;
      }
      float cold = p.c[b*512 + j];
      float cn = sigm(gq[1])*cold + sigm(gq[0])*tanh_f(gq[2]);
      float hn = sigm(gq[3])*tanh_f(cn);
      if (t < p.declen[b]){
        p.c[b*512 + j] = cn;
        p.h_bf16[b*512 + j] = f2bf(hn);
      }
    }
    gsync(p.sync, ++gen, blk);
  }
  // ===== epilogue: preds[T-1] from final h =====
  if (blk < 157){
    if (tid < 32) sm_dl[tid] = p.declen[tid];
    stage_h(p, a_lds, tid);
    __syncthreads();
    fc_stage(p, a_lds, sm_dl, blk, wv, la, lq, T_ - 1);
  }
}

// ---------------- host launcher ----------------

extern "C" void kernel_launch(void* const* d_in, const int* in_sizes, int n_in,
                              void* d_out, int out_size, void* d_ws, size_t ws_size,
                              hipStream_t stream){
  (void)in_sizes; (void)n_in; (void)out_size; (void)ws_size;
  KParams p;
  p.encoder_out = (const float*)d_in[0];
  p.captions    = (const int*)d_in[1];
  p.cap_lens    = (const int*)d_in[2];
  p.enc_att_w   = (const float*)d_in[3];  p.enc_att_b = (const float*)d_in[4];
  p.dec_att_w   = (const float*)d_in[5];  p.dec_att_b = (const float*)d_in[6];
  p.full_att_w  = (const float*)d_in[7];  p.full_att_b = (const float*)d_in[8];
  p.emb         = (const float*)d_in[9];
  p.init_h_w    = (const float*)d_in[10]; p.init_h_b = (const float*)d_in[11];
  p.init_c_w    = (const float*)d_in[12]; p.init_c_b = (const float*)d_in[13];
  p.f_beta_w    = (const float*)d_in[14]; p.f_beta_b = (const float*)d_in[15];
  p.lstm_w_ih   = (const float*)d_in[16]; p.lstm_w_hh = (const float*)d_in[17]; p.lstm_b = (const float*)d_in[18];
  p.fc_w        = (const float*)d_in[19]; p.fc_b = (const float*)d_in[20];

  float* out = (float*)d_out;
  p.out_preds   = out;                       // 6,400,000
  p.out_caps    = out + 6400000;             // 672
  p.out_declens = out + 6400672;             // 32
  p.out_alphas  = out + 6400704;             // 125,440
  p.out_sortind = out + 6526144;             // 32

  char* w = (char*)d_ws; size_t off = 0;
  auto alloc = [&](size_t bytes)->char*{ char* r = w + off; off = (off + bytes + 255) & ~(size_t)255; return r; };
  p.sort_ind  = (int*)alloc(128);
  p.declen    = (int*)alloc(128);
  p.caps_s    = (int*)alloc(2688);
  p.h_bf16    = (unsigned short*)alloc(32768);
  p.c         = (float*)alloc(65536);
  p.mean      = (float*)alloc(262144);
  p.enc_bf16  = (unsigned short*)alloc(25690112);
  p.waw_bf16  = (unsigned short*)alloc(2097152);
  p.wihE_bf16 = (unsigned short*)alloc(2097152);
  p.embs_bf16 = (unsigned short*)alloc(655360);
  p.att1      = (unsigned short*)alloc(6422528);   // [6272][512] bf16
  p.Wt        = (unsigned short*)alloc(15007744);  // [14656][512] bf16 (padded; rows 14608+ unread garbage, writes guarded)
  p.Wt2       = (unsigned short*)alloc(8388608);   // [2048][2048] bf16
  p.gpre      = (float*)alloc(5242880);
  p.s1out     = (float*)alloc(589824);             // [32][4608]
  p.awe_bf16  = (unsigned short*)alloc(131072);
  p.gpart     = (float*)alloc(2097152);            // 8 x [32][2048]
  p.sync      = (int*)alloc(8192);
  p.h0part    = (float*)p.gpart;                   // aliased: prologue-only

  hipMemsetAsync(p.sync, 0, 8192, stream);
  hipLaunchKernelGGL(k_meta,    dim3(1),     dim3(64),  0, stream, p);
  hipLaunchKernelGGL(k_encbf,   dim3(12544), dim3(256), 0, stream, p);
  hipLaunchKernelGGL(k_wbf,     dim3(2048),  dim3(256), 0, stream, p);
  hipLaunchKernelGGL(k_transpose, dim3(16*16),  dim3(256), 0, stream, p.dec_att_w, p.Wt,              512, 512);
  hipLaunchKernelGGL(k_transpose, dim3(16*64),  dim3(256), 0, stream, p.f_beta_w,  p.Wt + 512*512,    512, 2048);
  hipLaunchKernelGGL(k_transpose, dim3(16*64),  dim3(256), 0, stream, p.lstm_w_hh, p.Wt + 2560*512,   512, 2048);
  hipLaunchKernelGGL(k_transpose, dim3(16*313), dim3(256), 0, stream, p.fc_w,      p.Wt + 4608*512,   512, 10000);
  hipLaunchKernelGGL(k_transpose, dim3(64*64),  dim3(256), 0, stream, p.lstm_w_ih + 512*2048, p.Wt2, 2048, 2048);
  hipLaunchKernelGGL(k_mean,    dim3(128),   dim3(256), 0, stream, p);
  hipLaunchKernelGGL(k_h0c0,    dim3(64),    dim3(256), 0, stream, p);
  hipLaunchKernelGGL(k_h0c0red, dim3(128),   dim3(256), 0, stream, p);
  hipLaunchKernelGGL(k_embs,    dim3(320),   dim3(256), 0, stream, p);
  hipLaunchKernelGGL(k_gemm_bf16, dim3(80),  dim3(256), 0, stream,
                     (const unsigned short*)p.embs_bf16, (const unsigned short*)p.wihE_bf16,
                     p.lstm_b, p.gpre, 640, 2048, 512, 0);
  hipLaunchKernelGGL(k_gemm_bf16, dim3(196), dim3(256), 0, stream,
                     (const unsigned short*)p.enc_bf16, (const unsigned short*)p.waw_bf16,
                     p.enc_att_b, (float*)p.att1, 6272, 512, 2048, 1);

  void* args[] = { (void*)&p };
  hipLaunchCooperativeKernel((void*)k_loop, dim3(256), dim3(256), args, 0, stream);
}

// Round 4
// 2244.763 us; speedup vs baseline: 2.8941x; 1.0142x over previous
//
#include <hip/hip_runtime.h>

#define B_ 32
#define P_ 196
#define D_ 2048
#define A_ 512
#define E_ 512
#define H_ 512
#define V_ 10000
#define L_ 21
#define T_ 20
#define PP 200              /* padded P for encT rows */

typedef unsigned short us;

struct KParams {
  const float* encoder_out; const int* captions; const int* cap_lens;
  const float* enc_att_w; const float* enc_att_b;
  const float* dec_att_w; const float* dec_att_b;
  const float* full_att_w; const float* full_att_b;
  const float* emb;
  const float* init_h_w; const float* init_h_b;
  const float* init_c_w; const float* init_c_b;
  const float* f_beta_w; const float* f_beta_b;
  const float* lstm_w_ih; const float* lstm_w_hh; const float* lstm_b;
  const float* fc_w; const float* fc_b;
  float* out_preds; float* out_caps; float* out_declens; float* out_alphas; float* out_sortind;
  int* sort_ind; int* declen; int* caps_s;
  us* h_bf16; float* c; us* mean_bf16;
  us* waw_bf16; us* wihE_bf16; us* embs_bf16;
  us* att1; us* Wt; us* Wt2; us* Wt3; us* encT; us* awe_bf16;
  float* gpre; float* s1out;
  int* sync;
};

__device__ __forceinline__ us f2bf(float x){
  unsigned u = __float_as_uint(x);
  unsigned r = ((u >> 16) & 1u) + 0x7FFFu;
  return (us)((u + r) >> 16);
}
__device__ __forceinline__ unsigned pack2(float a, float b){
  return (unsigned)f2bf(a) | ((unsigned)f2bf(b) << 16);
}
__device__ __forceinline__ float bf2f(unsigned u16){ return __uint_as_float(u16 << 16); }
__device__ __forceinline__ float sigm(float x){ return 1.f/(1.f + __expf(-x)); }
__device__ __forceinline__ float tanh_f(float x){ return 1.f - 2.f/(__expf(2.f*x) + 1.f); }

// ---------------- prologue kernels ----------------

__global__ void k_meta(KParams p){
  __shared__ int len[32], sidx[32], sdecl[32];
  int tid = threadIdx.x;
  if (tid < 32) len[tid] = p.cap_lens[tid];
  __syncthreads();
  if (tid == 0){
    bool used[32];
    for (int i = 0; i < 32; i++) used[i] = false;
    for (int r = 0; r < 32; r++){
      int best = -1, bl = -2;
      for (int i = 0; i < 32; i++) if (!used[i] && len[i] > bl){ bl = len[i]; best = i; }
      used[best] = true; sidx[r] = best; sdecl[r] = bl - 1;
    }
  }
  __syncthreads();
  if (tid < 32){
    p.sort_ind[tid] = sidx[tid]; p.out_sortind[tid] = (float)sidx[tid];
    p.declen[tid]   = sdecl[tid]; p.out_declens[tid] = (float)sdecl[tid];
  }
  for (int idx = tid; idx < B_*L_; idx += 64){
    int b = idx / L_, l = idx - b*L_;
    int cv = p.captions[sidx[b]*L_ + l];
    p.caps_s[idx] = cv; p.out_caps[idx] = (float)cv;
  }
}

// transpose one 32x32 tile: src fp32 [R][C] -> dst bf16 [C][Rp] (rows >= R zero)
__device__ void tp_tile(const float* src, us* dst, int R, int C, int Rp, int bi){
  __shared__ float tl[32][33];
  int tilesC = (C + 31) >> 5;
  int tr = bi / tilesC, tc = bi - tr*tilesC;
  int r0 = tr << 5, c0 = tc << 5;
  int tid = threadIdx.x;
  int r = tid >> 3, cs = (tid & 7) << 2;
  #pragma unroll
  for (int i = 0; i < 4; i++){
    int c = c0 + cs + i;
    tl[r][cs + i] = (r0 + r < R && c < C) ? src[(size_t)(r0 + r)*C + c] : 0.f;
  }
  __syncthreads();
  int c = tid >> 3, rs = (tid & 7) << 2;
  if (c0 + c < C && r0 + rs < Rp){
    unsigned lo = pack2(tl[rs][c], tl[rs+1][c]);
    unsigned hi = pack2(tl[rs+2][c], tl[rs+3][c]);
    *(uint2*)(dst + (size_t)(c0 + c)*Rp + r0 + rs) = make_uint2(lo, hi);
  }
}

// fused weight prep: bf16 casts + all transposes + emb gather + encT
__global__ void k_prep(KParams p){
  int bi = blockIdx.x, tid = threadIdx.x;
  if (bi < 2048){                         // enc_att_w, lstm_w_ih[:512] -> bf16 row-major
    int q = bi*256 + tid;
    const float4* src; uint2* dst; int qq;
    if (q < 262144){ src = (const float4*)p.enc_att_w; dst = (uint2*)p.waw_bf16;  qq = q; }
    else           { src = (const float4*)p.lstm_w_ih; dst = (uint2*)p.wihE_bf16; qq = q - 262144; }
    float4 v = src[qq];
    dst[qq] = make_uint2(pack2(v.x, v.y), pack2(v.z, v.w));
  } else if (bi < 2304){  tp_tile(p.dec_att_w, p.Wt,               512, 512,   512,  bi - 2048);
  } else if (bi < 3328){  tp_tile(p.f_beta_w,  p.Wt + 512*512,     512, 2048,  512,  bi - 2304);
  } else if (bi < 4352){  tp_tile(p.lstm_w_hh, p.Wt + 2560*512,    512, 2048,  512,  bi - 3328);
  } else if (bi < 9360){  tp_tile(p.fc_w,      p.Wt + 4608*512,    512, 10000, 512,  bi - 4352);
  } else if (bi < 13456){ tp_tile(p.lstm_w_ih + 512*2048, p.Wt2,   2048, 2048, 2048, bi - 9360);
  } else if (bi < 14480){ tp_tile(p.init_h_w,  p.Wt3,              2048, 512,  2048, bi - 13456);
  } else if (bi < 15504){ tp_tile(p.init_c_w,  p.Wt3 + 512*2048,   2048, 512,  2048, bi - 14480);
  } else if (bi < 15824){                 // embs gather -> bf16 [t][b][512]
    int q = (bi - 15504)*256 + tid;       // 81920 quads
    int row = q >> 7, qi = q & 127;
    int t = row >> 5, b = row & 31;
    int cap = p.caps_s[b*L_ + t];
    float4 v = ((const float4*)(p.emb + (size_t)cap*E_))[qi];
    ((uint2*)p.embs_bf16)[q] = make_uint2(pack2(v.x, v.y), pack2(v.z, v.w));
  } else {                                // encT: sorted enc -> bf16 [b][d][PP]
    int bl = bi - 15824;                  // 32*448 blocks
    int b = bl / 448, ti = bl - b*448;
    tp_tile(p.encoder_out + (size_t)p.sort_ind[b]*(P_*D_), p.encT + (size_t)b*D_*PP,
            196, 2048, PP, ti);
  }
}

// ---------------- generic bf16 MFMA GEMM (128x128 tile) ----------------
using bf16x8 = __attribute__((ext_vector_type(8))) short;
using f32x4  = __attribute__((ext_vector_type(4))) float;

// mode 0: Aq bf16 [M][K].  mode 1: gather rows from fp32 Af (sorted enc), K=2048.
__global__ void __launch_bounds__(256) k_gemm_bf16(const us* Aq, const float* Af, const int* sidx,
                                                   const us* Bq, const float* bias, float* C,
                                                   int M, int N, int K, int obf, int mode){
  __shared__ us a_lds[128][40];
  __shared__ us b_lds[128][40];
  int ntiles = N >> 7;
  int bm = (blockIdx.x / ntiles) << 7;
  int bn = (blockIdx.x % ntiles) << 7;
  int tid = threadIdx.x;
  int wave = tid >> 6, lane = tid & 63;
  int wr = (wave >> 1) << 6, wc = (wave & 1) << 6;
  int la = lane & 15, lq = lane >> 4;
  f32x4 acc[4][4] = {};
  for (int k0 = 0; k0 < K; k0 += 32){
    {
      int r = tid >> 1, ch = (tid & 1) << 4;
      if (mode == 0){
        const uint4* asrc = (const uint4*)(Aq + (size_t)(bm + r)*K + k0 + ch);
        uint4 v0 = asrc[0], v1 = asrc[1];
        *(uint4*)&a_lds[r][ch]     = v0;
        *(uint4*)&a_lds[r][ch + 8] = v1;
      } else {
        int g = bm + r; int b = g / 196; int pp = g - b*196;
        const float4* as = (const float4*)(Af + ((size_t)sidx[b]*196 + pp)*2048 + k0 + ch);
        float4 f0 = as[0], f1 = as[1], f2 = as[2], f3 = as[3];
        *(uint4*)&a_lds[r][ch]     = make_uint4(pack2(f0.x,f0.y), pack2(f0.z,f0.w), pack2(f1.x,f1.y), pack2(f1.z,f1.w));
        *(uint4*)&a_lds[r][ch + 8] = make_uint4(pack2(f2.x,f2.y), pack2(f2.z,f2.w), pack2(f3.x,f3.y), pack2(f3.z,f3.w));
      }
      int kk = tid >> 3, n0 = (tid & 7) << 4;
      const us* bs = Bq + (size_t)(k0 + kk)*N + bn + n0;
      uint4 bv0 = *(const uint4*)bs, bv1 = *(const uint4*)(bs + 8);
      unsigned vals[8] = {bv0.x, bv0.y, bv0.z, bv0.w, bv1.x, bv1.y, bv1.z, bv1.w};
      #pragma unroll
      for (int i = 0; i < 8; i++){
        b_lds[n0 + 2*i][kk]     = (us)(vals[i] & 0xffffu);
        b_lds[n0 + 2*i + 1][kk] = (us)(vals[i] >> 16);
      }
    }
    __syncthreads();
    bf16x8 af[4], bfr[4];
    #pragma unroll
    for (int mt = 0; mt < 4; mt++) af[mt]  = *(const bf16x8*)&a_lds[wr + mt*16 + la][lq*8];
    #pragma unroll
    for (int nt = 0; nt < 4; nt++) bfr[nt] = *(const bf16x8*)&b_lds[wc + nt*16 + la][lq*8];
    #pragma unroll
    for (int mt = 0; mt < 4; mt++)
      #pragma unroll
      for (int nt = 0; nt < 4; nt++)
        acc[mt][nt] = __builtin_amdgcn_mfma_f32_16x16x32_bf16(af[mt], bfr[nt], acc[mt][nt], 0, 0, 0);
    __syncthreads();
  }
  #pragma unroll
  for (int mt = 0; mt < 4; mt++){
    int row0 = bm + wr + mt*16 + lq*4;
    #pragma unroll
    for (int nt = 0; nt < 4; nt++){
      int coln = bn + wc + nt*16 + la;
      float bb = bias ? bias[coln] : 0.f;
      #pragma unroll
      for (int r = 0; r < 4; r++){
        float v = acc[mt][nt][r] + bb;
        if (obf) ((us*)C)[(size_t)(row0 + r)*N + coln] = f2bf(v);
        else     C[(size_t)(row0 + r)*N + coln] = v;
      }
    }
  }
}

// ---------------- cooperative scan kernel ----------------
// Tree barrier: 32 arrival lines -> 1 master -> 64 spread flag lines.
// Last-arriver detection via fetch_add return values; no centralized polling.

__device__ __forceinline__ void gsync(int* sc, int gen, int blk){
  __syncthreads();
  if (threadIdx.x == 0){
    int old = __hip_atomic_fetch_add(&sc[(blk & 31)*16], 1, __ATOMIC_ACQ_REL, __HIP_MEMORY_SCOPE_AGENT);
    bool done = false;
    if (old == gen*8 - 1){
      int old2 = __hip_atomic_fetch_add(&sc[512], 1, __ATOMIC_ACQ_REL, __HIP_MEMORY_SCOPE_AGENT);
      if (old2 == gen*32 - 1){
        __builtin_amdgcn_fence(__ATOMIC_ACQ_REL, "agent");
        #pragma unroll
        for (int i = 0; i < 64; i++)
          __hip_atomic_store(&sc[576 + i*16], gen, __ATOMIC_RELAXED, __HIP_MEMORY_SCOPE_AGENT);
        done = true;
      }
    }
    if (!done){
      while (__hip_atomic_load(&sc[576 + (blk >> 2)*16], __ATOMIC_RELAXED, __HIP_MEMORY_SCOPE_AGENT) < gen)
        __builtin_amdgcn_s_sleep(1);
      __builtin_amdgcn_fence(__ATOMIC_ACQUIRE, "agent");
    }
  }
  __syncthreads();
}

__device__ __forceinline__ void stage_h(const KParams& p, us (*a_lds)[520], int tid){
  int row = tid >> 3, seg = tid & 7;
  const uint4* src = (const uint4*)(p.h_bf16 + row*512 + seg*64);
  uint4* dst = (uint4*)&a_lds[row][seg*64];
  #pragma unroll
  for (int i = 0; i < 8; i++) dst[i] = src[i];
}

__device__ __forceinline__ void fc_stage(const KParams& p, us (*a_lds)[520],
                                         const int* sm_dl, int g, int wv, int la, int lq, int tpred){
  int n0g = g*64 + wv*16;
  const us* wp = p.Wt + (size_t)(4608 + n0g + la)*512 + lq*8;
  bf16x8 bw[16];
  #pragma unroll
  for (int ks = 0; ks < 16; ks++) bw[ks] = *(const bf16x8*)(wp + ks*32);
  f32x4 ac0 = {}, ac1 = {};
  #pragma unroll
  for (int ks = 0; ks < 16; ks++){
    bf16x8 a0 = *(const bf16x8*)&a_lds[la][ks*32 + lq*8];
    bf16x8 a1 = *(const bf16x8*)&a_lds[16 + la][ks*32 + lq*8];
    ac0 = __builtin_amdgcn_mfma_f32_16x16x32_bf16(a0, bw[ks], ac0, 0, 0, 0);
    ac1 = __builtin_amdgcn_mfma_f32_16x16x32_bf16(a1, bw[ks], ac1, 0, 0, 0);
  }
  int v = n0g + la;
  if (v < V_){
    float bb = p.fc_b[v];
    #pragma unroll
    for (int mt = 0; mt < 2; mt++){
      f32x4 ac = mt ? ac1 : ac0;
      #pragma unroll
      for (int r = 0; r < 4; r++){
        int b = mt*16 + lq*4 + r;
        bool act = tpred < sm_dl[b];
        p.out_preds[((size_t)b*T_ + tpred)*V_ + v] = act ? (ac[r] + bb) : 0.f;
      }
    }
  }
}

__global__ void __launch_bounds__(256, 1) k_loop(KParams p){
  const int tid = threadIdx.x, blk = blockIdx.x;
  const int wv = tid >> 6, lane = tid & 63;
  const int la = lane & 15, lq = lane >> 4;
  __shared__ us a_lds[32][520];
  __shared__ float sm_att2[512], sm_fw[512], sm_e[224], sm_red[16], sm_alpha[224];
  __shared__ int sm_dl[32];
  __shared__ f32x4 sm_p[4][2][64];
  __shared__ float g_lds[32][16];
  int gen = 0;

  if (tid < 32) sm_dl[tid] = p.declen[tid];
  __syncthreads();

  // ===== P1: mean over p from encT (256 blocks) =====
  {
    int b = blk >> 3, d = (blk & 7)*256 + tid;
    const uint4* rp_ = (const uint4*)(p.encT + ((size_t)b*D_ + d)*PP);
    float s = 0.f;
    #pragma unroll 5
    for (int i = 0; i < 25; i++){
      uint4 u = rp_[i];
      s += bf2f(u.x&0xffffu) + bf2f(u.x>>16) + bf2f(u.y&0xffffu) + bf2f(u.y>>16)
         + bf2f(u.z&0xffffu) + bf2f(u.z>>16) + bf2f(u.w&0xffffu) + bf2f(u.w>>16);
    }
    p.mean_bf16[(size_t)b*D_ + d] = f2bf(s * (1.f/196.f));
  }
  gsync(p.sync, ++gen, blk);
  // ===== P2: h0/c0 = mean @ Wt3 (64 blocks, 4-wave K-split) =====
  if (blk < 64){
    int col = blk*16 + la;
    const us* wp = p.Wt3 + (size_t)col*2048 + wv*512 + lq*8;
    bf16x8 bw[16];
    #pragma unroll
    for (int ks = 0; ks < 16; ks++) bw[ks] = *(const bf16x8*)(wp + ks*32);
    f32x4 ac0 = {}, ac1 = {};
    #pragma unroll
    for (int ks = 0; ks < 16; ks++){
      bf16x8 a0 = *(const bf16x8*)(p.mean_bf16 + (size_t)la*2048      + wv*512 + ks*32 + lq*8);
      bf16x8 a1 = *(const bf16x8*)(p.mean_bf16 + (size_t)(la+16)*2048 + wv*512 + ks*32 + lq*8);
      ac0 = __builtin_amdgcn_mfma_f32_16x16x32_bf16(a0, bw[ks], ac0, 0, 0, 0);
      ac1 = __builtin_amdgcn_mfma_f32_16x16x32_bf16(a1, bw[ks], ac1, 0, 0, 0);
    }
    sm_p[wv][0][lane] = ac0; sm_p[wv][1][lane] = ac1;
    __syncthreads();
    if (wv == 0){
      #pragma unroll
      for (int h2 = 0; h2 < 2; h2++){
        f32x4 s = sm_p[0][h2][lane]; 
        #pragma unroll
        for (int w = 1; w < 4; w++) s += sm_p[w][h2][lane];
        #pragma unroll
        for (int r = 0; r < 4; r++){
          int b = h2*16 + lq*4 + r;
          if (col < 512) p.h_bf16[b*512 + col] = f2bf(s[r] + p.init_h_b[col]);
          else           p.c[b*512 + col - 512] = s[r] + p.init_c_b[col - 512];
        }
      }
    }
  }
  gsync(p.sync, ++gen, blk);

  for (int t = 0; t < T_; ++t){
    // ===== S1: h @ Wt -> att2|gate|ghh (72 blocks) =====
    if (blk < 72){
      stage_h(p, a_lds, tid);
      __syncthreads();
      int n0 = blk*64 + wv*16;
      const us* wp = p.Wt + (size_t)(n0 + la)*512 + lq*8;
      bf16x8 bw[16];
      #pragma unroll
      for (int ks = 0; ks < 16; ks++) bw[ks] = *(const bf16x8*)(wp + ks*32);
      f32x4 ac0 = {}, ac1 = {};
      #pragma unroll
      for (int ks = 0; ks < 16; ks++){
        bf16x8 a0 = *(const bf16x8*)&a_lds[la][ks*32 + lq*8];
        bf16x8 a1 = *(const bf16x8*)&a_lds[16 + la][ks*32 + lq*8];
        ac0 = __builtin_amdgcn_mfma_f32_16x16x32_bf16(a0, bw[ks], ac0, 0, 0, 0);
        ac1 = __builtin_amdgcn_mfma_f32_16x16x32_bf16(a1, bw[ks], ac1, 0, 0, 0);
      }
      int col = n0 + la;
      #pragma unroll
      for (int mt = 0; mt < 2; mt++){
        f32x4 ac = mt ? ac1 : ac0;
        #pragma unroll
        for (int r = 0; r < 4; r++) p.s1out[(mt*16 + lq*4 + r)*4608 + col] = ac[r];
      }
    }
    gsync(p.sync, ++gen, blk);
    // ===== S2: attention (blocks 0..31) | fc preds[t-1] (blocks 32..188) =====
    if (blk < 32){
      int b = blk;
      for (int cc = tid; cc < 512; cc += 256){
        sm_att2[cc] = p.s1out[b*4608 + cc] + p.dec_att_b[cc];
        sm_fw[cc]   = p.full_att_w[cc];
      }
      __syncthreads();
      float ee = -1e30f;
      if (tid < 196){
        const uint4* row = (const uint4*)(p.att1 + ((size_t)(b*196 + tid))*512);
        float s = 0.f;
        #pragma unroll 8
        for (int i = 0; i < 64; i++){
          uint4 u = row[i];
          float4 a0 = *(const float4*)&sm_att2[i*8], a1 = *(const float4*)&sm_att2[i*8+4];
          float4 f0 = *(const float4*)&sm_fw[i*8],   f1 = *(const float4*)&sm_fw[i*8+4];
          s += fmaxf(bf2f(u.x&0xffffu)+a0.x,0.f)*f0.x + fmaxf(bf2f(u.x>>16)+a0.y,0.f)*f0.y
             + fmaxf(bf2f(u.y&0xffffu)+a0.z,0.f)*f0.z + fmaxf(bf2f(u.y>>16)+a0.w,0.f)*f0.w
             + fmaxf(bf2f(u.z&0xffffu)+a1.x,0.f)*f1.x + fmaxf(bf2f(u.z>>16)+a1.y,0.f)*f1.y
             + fmaxf(bf2f(u.w&0xffffu)+a1.z,0.f)*f1.z + fmaxf(bf2f(u.w>>16)+a1.w,0.f)*f1.w;
        }
        ee = s;
      }
      float v = ee;
      #pragma unroll
      for (int off = 32; off; off >>= 1) v = fmaxf(v, __shfl_xor(v, off));
      if (lane == 0) sm_red[wv] = v;
      __syncthreads();
      float m = fmaxf(fmaxf(sm_red[0], sm_red[1]), fmaxf(sm_red[2], sm_red[3]));
      float ex = (tid < 196) ? __expf(ee - m) : 0.f;
      float sv = ex;
      #pragma unroll
      for (int off = 32; off; off >>= 1) sv += __shfl_xor(sv, off);
      if (lane == 0) sm_red[4 + wv] = sv;
      __syncthreads();
      float ssum = sm_red[4] + sm_red[5] + sm_red[6] + sm_red[7];
      if (tid < 196){
        float a = ex/ssum;
        sm_alpha[tid] = a;
        bool act = t < sm_dl[b];
        p.out_alphas[((size_t)b*T_ + t)*P_ + tid] = act ? a : 0.f;
      } else if (tid < 200) sm_alpha[tid] = 0.f;
      __syncthreads();
      // awe: thread owns 8 d-cols; encT rows contiguous
      int d0 = tid*8;
      float aw[8];
      #pragma unroll
      for (int r = 0; r < 8; r++){
        const uint4* rp_ = (const uint4*)(p.encT + ((size_t)b*D_ + d0 + r)*PP);
        float acc = 0.f;
        #pragma unroll 5
        for (int i = 0; i < 25; i++){
          uint4 u = rp_[i];
          float4 alo = *(const float4*)&sm_alpha[i*8], ahi = *(const float4*)&sm_alpha[i*8+4];
          acc += alo.x*bf2f(u.x&0xffffu) + alo.y*bf2f(u.x>>16)
               + alo.z*bf2f(u.y&0xffffu) + alo.w*bf2f(u.y>>16)
               + ahi.x*bf2f(u.z&0xffffu) + ahi.y*bf2f(u.z>>16)
               + ahi.z*bf2f(u.w&0xffffu) + ahi.w*bf2f(u.w>>16);
        }
        aw[r] = acc;
      }
      float4 q1 = *(const float4*)(p.s1out + b*4608 + 512 + d0);
      float4 q2 = *(const float4*)(p.s1out + b*4608 + 512 + d0 + 4);
      float4 b1 = *(const float4*)(p.f_beta_b + d0);
      float4 b2 = *(const float4*)(p.f_beta_b + d0 + 4);
      uint4 outp;
      outp.x = pack2(aw[0]*sigm(q1.x+b1.x), aw[1]*sigm(q1.y+b1.y));
      outp.y = pack2(aw[2]*sigm(q1.z+b1.z), aw[3]*sigm(q1.w+b1.w));
      outp.z = pack2(aw[4]*sigm(q2.x+b2.x), aw[5]*sigm(q2.y+b2.y));
      outp.w = pack2(aw[6]*sigm(q2.z+b2.z), aw[7]*sigm(q2.w+b2.w));
      *(uint4*)(p.awe_bf16 + b*2048 + d0) = outp;
    } else if (blk < 189 && t > 0){
      stage_h(p, a_lds, tid);
      __syncthreads();
      fc_stage(p, a_lds, sm_dl, blk - 32, wv, la, lq, t - 1);
    }
    gsync(p.sync, ++gen, blk);
    // ===== S45: awe @ Wt2 (gate-sliced, 128 blocks) + LSTM cell =====
    if (blk < 128){
      int z = blk;
      int colg = (la >> 2)*512 + z*4 + (la & 3);
      const us* wp = p.Wt2 + (size_t)colg*2048 + wv*512 + lq*8;
      bf16x8 bw[16];
      #pragma unroll
      for (int ks = 0; ks < 16; ks++) bw[ks] = *(const bf16x8*)(wp + ks*32);
      f32x4 ac0 = {}, ac1 = {};
      #pragma unroll
      for (int ks = 0; ks < 16; ks++){
        bf16x8 a0 = *(const bf16x8*)(p.awe_bf16 + (size_t)la*2048      + wv*512 + ks*32 + lq*8);
        bf16x8 a1 = *(const bf16x8*)(p.awe_bf16 + (size_t)(la+16)*2048 + wv*512 + ks*32 + lq*8);
        ac0 = __builtin_amdgcn_mfma_f32_16x16x32_bf16(a0, bw[ks], ac0, 0, 0, 0);
        ac1 = __builtin_amdgcn_mfma_f32_16x16x32_bf16(a1, bw[ks], ac1, 0, 0, 0);
      }
      sm_p[wv][0][lane] = ac0; sm_p[wv][1][lane] = ac1;
      __syncthreads();
      if (wv == 0){
        #pragma unroll
        for (int h2 = 0; h2 < 2; h2++){
          f32x4 s = sm_p[0][h2][lane];
          #pragma unroll
          for (int w = 1; w < 4; w++) s += sm_p[w][h2][lane];
          #pragma unroll
          for (int r = 0; r < 4; r++) g_lds[h2*16 + lq*4 + r][la] = s[r];
        }
      }
      __syncthreads();
      if (tid < 128){
        int b = tid >> 2, j = tid & 3;
        float gv[4];
        #pragma unroll
        for (int q = 0; q < 4; q++){
          int cl = q*512 + z*4 + j;
          gv[q] = g_lds[b][q*4 + j] + p.s1out[b*4608 + 2560 + cl]
                + p.gpre[((size_t)t*32 + b)*2048 + cl];
        }
        int hc = z*4 + j;
        float cold = p.c[b*512 + hc];
        float cn = sigm(gv[1])*cold + sigm(gv[0])*tanh_f(gv[2]);
        float hn = sigm(gv[3])*tanh_f(cn);
        if (t < sm_dl[b]){
          p.c[b*512 + hc] = cn;
          p.h_bf16[b*512 + hc] = f2bf(hn);
        }
      }
    }
    gsync(p.sync, ++gen, blk);
  }
  // ===== epilogue: preds[T-1] =====
  if (blk < 157){
    stage_h(p, a_lds, tid);
    __syncthreads();
    fc_stage(p, a_lds, sm_dl, blk, wv, la, lq, T_ - 1);
  }
}

// ---------------- host launcher ----------------

extern "C" void kernel_launch(void* const* d_in, const int* in_sizes, int n_in,
                              void* d_out, int out_size, void* d_ws, size_t ws_size,
                              hipStream_t stream){
  (void)in_sizes; (void)n_in; (void)out_size; (void)ws_size;
  KParams p;
  p.encoder_out = (const float*)d_in[0];
  p.captions    = (const int*)d_in[1];
  p.cap_lens    = (const int*)d_in[2];
  p.enc_att_w   = (const float*)d_in[3];  p.enc_att_b = (const float*)d_in[4];
  p.dec_att_w   = (const float*)d_in[5];  p.dec_att_b = (const float*)d_in[6];
  p.full_att_w  = (const float*)d_in[7];  p.full_att_b = (const float*)d_in[8];
  p.emb         = (const float*)d_in[9];
  p.init_h_w    = (const float*)d_in[10]; p.init_h_b = (const float*)d_in[11];
  p.init_c_w    = (const float*)d_in[12]; p.init_c_b = (const float*)d_in[13];
  p.f_beta_w    = (const float*)d_in[14]; p.f_beta_b = (const float*)d_in[15];
  p.lstm_w_ih   = (const float*)d_in[16]; p.lstm_w_hh = (const float*)d_in[17]; p.lstm_b = (const float*)d_in[18];
  p.fc_w        = (const float*)d_in[19]; p.fc_b = (const float*)d_in[20];

  float* out = (float*)d_out;
  p.out_preds   = out;
  p.out_caps    = out + 6400000;
  p.out_declens = out + 6400672;
  p.out_alphas  = out + 6400704;
  p.out_sortind = out + 6526144;

  char* w = (char*)d_ws; size_t off = 0;
  auto alloc = [&](size_t bytes)->char*{ char* r = w + off; off = (off + bytes + 255) & ~(size_t)255; return r; };
  p.sort_ind  = (int*)alloc(128);
  p.declen    = (int*)alloc(128);
  p.caps_s    = (int*)alloc(2688);
  p.h_bf16    = (us*)alloc(32768);
  p.c         = (float*)alloc(65536);
  p.mean_bf16 = (us*)alloc(131072);
  p.waw_bf16  = (us*)alloc(2097152);
  p.wihE_bf16 = (us*)alloc(2097152);
  p.embs_bf16 = (us*)alloc(655360);
  p.att1      = (us*)alloc(6422528);    // [6272][512]
  p.Wt        = (us*)alloc(15007744);   // [14656][512] (rows >=14608 garbage, writes guarded)
  p.Wt2       = (us*)alloc(8388608);    // [2048][2048]
  p.Wt3       = (us*)alloc(4194304);    // [1024][2048]
  p.encT      = (us*)alloc(26214400);   // [32][2048][200]
  p.gpre      = (float*)alloc(5242880); // [20][32][2048]
  p.s1out     = (float*)alloc(589824);  // [32][4608]
  p.awe_bf16  = (us*)alloc(131072);
  p.sync      = (int*)alloc(8192);

  hipMemsetAsync(p.sync, 0, 8192, stream);
  hipLaunchKernelGGL(k_meta, dim3(1),     dim3(64),  0, stream, p);
  hipLaunchKernelGGL(k_prep, dim3(30160), dim3(256), 0, stream, p);
  hipLaunchKernelGGL(k_gemm_bf16, dim3(80),  dim3(256), 0, stream,
                     (const us*)p.embs_bf16, (const float*)nullptr, (const int*)nullptr,
                     (const us*)p.wihE_bf16, p.lstm_b, p.gpre, 640, 2048, 512, 0, 0);
  hipLaunchKernelGGL(k_gemm_bf16, dim3(196), dim3(256), 0, stream,
                     (const us*)nullptr, p.encoder_out, (const int*)p.sort_ind,
                     (const us*)p.waw_bf16, p.enc_att_b, (float*)p.att1, 6272, 512, 2048, 1, 1);

  void* args[] = { (void*)&p };
  hipLaunchCooperativeKernel((void*)k_loop, dim3(256), dim3(256), args, 0, stream);
}

// Round 5
// 1977.373 us; speedup vs baseline: 3.2854x; 1.1352x over previous
//
#include <hip/hip_runtime.h>

#define B_ 32
#define P_ 196
#define D_ 2048
#define A_ 512
#define E_ 512
#define H_ 512
#define V_ 10000
#define L_ 21
#define T_ 20
#define PP 208              /* padded P for encT rows (mult of 16) */

typedef unsigned short us;

struct KParams {
  const float* encoder_out; const int* captions; const int* cap_lens;
  const float* enc_att_w; const float* enc_att_b;
  const float* dec_att_w; const float* dec_att_b;
  const float* full_att_w; const float* full_att_b;
  const float* emb;
  const float* init_h_w; const float* init_h_b;
  const float* init_c_w; const float* init_c_b;
  const float* f_beta_w; const float* f_beta_b;
  const float* lstm_w_ih; const float* lstm_w_hh; const float* lstm_b;
  const float* fc_w; const float* fc_b;
  float* out_preds; float* out_caps; float* out_declens; float* out_alphas; float* out_sortind;
  int* sort_ind; int* declen; int* caps_s;
  us* h_bf16; float* c; us* mean_bf16;
  us* waw_bf16; us* wihE_bf16; us* embs_bf16;
  us* att1; us* Wt; us* Wt2; us* Wt3; us* encT; us* awe_bf16;
  float* gpre; float* s1out; float* alpha_g;
  int* sync;
};

__device__ __forceinline__ us f2bf(float x){
  unsigned u = __float_as_uint(x);
  unsigned r = ((u >> 16) & 1u) + 0x7FFFu;
  return (us)((u + r) >> 16);
}
__device__ __forceinline__ unsigned pack2(float a, float b){
  return (unsigned)f2bf(a) | ((unsigned)f2bf(b) << 16);
}
__device__ __forceinline__ float bf2f(unsigned u16){ return __uint_as_float(u16 << 16); }
__device__ __forceinline__ float sigm(float x){ return 1.f/(1.f + __expf(-x)); }
__device__ __forceinline__ float tanh_f(float x){ return 1.f - 2.f/(__expf(2.f*x) + 1.f); }

using bf16x8 = __attribute__((ext_vector_type(8))) short;
using f32x4  = __attribute__((ext_vector_type(4))) float;
#define MFMA(a,b,c) __builtin_amdgcn_mfma_f32_16x16x32_bf16((a),(b),(c),0,0,0)

// ---------------- prologue kernels ----------------

__global__ void k_meta(KParams p){
  __shared__ int len[32], sidx[32], sdecl[32];
  int tid = threadIdx.x;
  if (tid < 32) len[tid] = p.cap_lens[tid];
  __syncthreads();
  if (tid == 0){
    bool used[32];
    for (int i = 0; i < 32; i++) used[i] = false;
    for (int r = 0; r < 32; r++){
      int best = -1, bl = -2;
      for (int i = 0; i < 32; i++) if (!used[i] && len[i] > bl){ bl = len[i]; best = i; }
      used[best] = true; sidx[r] = best; sdecl[r] = bl - 1;
    }
  }
  __syncthreads();
  if (tid < 32){
    p.sort_ind[tid] = sidx[tid]; p.out_sortind[tid] = (float)sidx[tid];
    p.declen[tid]   = sdecl[tid]; p.out_declens[tid] = (float)sdecl[tid];
  }
  for (int idx = tid; idx < B_*L_; idx += 64){
    int b = idx / L_, l = idx - b*L_;
    int cv = p.captions[sidx[b]*L_ + l];
    p.caps_s[idx] = cv; p.out_caps[idx] = (float)cv;
  }
}

// 64x64 tile transpose: fp32 [R][C] -> bf16 [C][Rp], zero-pad rows >= R
__device__ void tp64(const float* src, us* dst, int R, int C, int Rp, int bi){
  __shared__ float tl[64][68];
  int tilesC = (C + 63) >> 6;
  int tr = bi / tilesC, tc = bi - tr*tilesC;
  int r0 = tr << 6, c0 = tc << 6;
  int tid = threadIdx.x;
  {
    int r = tid >> 2, cs = (tid & 3) << 4;
    bool rok = (r0 + r) < R;
    #pragma unroll
    for (int i = 0; i < 4; i++){
      int c = c0 + cs + i*4;
      float4 v = make_float4(0.f, 0.f, 0.f, 0.f);
      if (rok && c < C) v = *(const float4*)(src + (size_t)(r0 + r)*C + c);
      *(float4*)&tl[r][cs + i*4] = v;
    }
  }
  __syncthreads();
  {
    int c = tid >> 2, rs = (tid & 3) << 4;
    if (c0 + c < C && r0 + rs < Rp){
      us tmp[16];
      #pragma unroll
      for (int i = 0; i < 16; i++) tmp[i] = f2bf(tl[rs + i][c]);
      *(uint4*)(dst + (size_t)(c0 + c)*Rp + r0 + rs)     = *(uint4*)&tmp[0];
      *(uint4*)(dst + (size_t)(c0 + c)*Rp + r0 + rs + 8) = *(uint4*)&tmp[8];
    }
  }
}

__global__ void k_prep(KParams p){
  int bi = blockIdx.x, tid = threadIdx.x;
  if (bi < 512){                         // casts: enc_att_w, lstm_w_ih[:512]
    #pragma unroll
    for (int i = 0; i < 4; i++){
      int q = bi*1024 + i*256 + tid;
      const float4* src; uint2* dst; int qq;
      if (q < 262144){ src = (const float4*)p.enc_att_w; dst = (uint2*)p.waw_bf16;  qq = q; }
      else           { src = (const float4*)p.lstm_w_ih; dst = (uint2*)p.wihE_bf16; qq = q - 262144; }
      float4 v = src[qq];
      dst[qq] = make_uint2(pack2(v.x, v.y), pack2(v.z, v.w));
    }
  } else if (bi < 576){   tp64(p.dec_att_w, p.Wt,             512, 512,   512,  bi - 512);
  } else if (bi < 832){   tp64(p.f_beta_w,  p.Wt + 512*512,   512, 2048,  512,  bi - 576);
  } else if (bi < 1088){  tp64(p.lstm_w_hh, p.Wt + 2560*512,  512, 2048,  512,  bi - 832);
  } else if (bi < 2344){  tp64(p.fc_w,      p.Wt + 4608*512,  512, 10000, 512,  bi - 1088);
  } else if (bi < 3368){  tp64(p.lstm_w_ih + 512*2048, p.Wt2, 2048, 2048, 2048, bi - 2344);
  } else if (bi < 3624){  tp64(p.init_h_w,  p.Wt3,            2048, 512,  2048, bi - 3368);
  } else if (bi < 3880){  tp64(p.init_c_w,  p.Wt3 + 512*2048, 2048, 512,  2048, bi - 3624);
  } else if (bi < 4200){                 // embs gather -> bf16 [t][b][512]
    int q = (bi - 3880)*256 + tid;
    int row = q >> 7, qi = q & 127;
    int t = row >> 5, b = row & 31;
    int cap = p.caps_s[b*L_ + t];
    float4 v = ((const float4*)(p.emb + (size_t)cap*E_))[qi];
    ((uint2*)p.embs_bf16)[q] = make_uint2(pack2(v.x, v.y), pack2(v.z, v.w));
  } else {                               // encT: sorted enc [196][2048] -> [2048][208]
    int bl = bi - 4200;                  // 32*128
    int b = bl >> 7, ti = bl & 127;
    tp64(p.encoder_out + (size_t)p.sort_ind[b]*(P_*D_), p.encT + (size_t)b*D_*PP,
         196, 2048, PP, ti);
  }
}

// fused prologue GEMMs: bi<196 att1 (enc@enc_att_w, gathered fp32 A), else gpre (embs@wihE)
__global__ void __launch_bounds__(256) k_gemm2(KParams p){
  __shared__ us a_lds[128][40];
  __shared__ us b_lds[128][40];
  int bi = blockIdx.x;
  const us* Aq = nullptr; const float* Af = nullptr; const int* sidx = nullptr;
  const us* Bq; const float* bias; float* C; int N, K, obf, mode, ti;
  if (bi < 196){
    Af = p.encoder_out; sidx = p.sort_ind; Bq = p.waw_bf16; bias = p.enc_att_b;
    C = (float*)p.att1; N = 512; K = 2048; obf = 1; mode = 1; ti = bi;
  } else {
    Aq = p.embs_bf16; Bq = p.wihE_bf16; bias = p.lstm_b;
    C = p.gpre; N = 2048; K = 512; obf = 0; mode = 0; ti = bi - 196;
  }
  int ntiles = N >> 7;
  int bm = (ti / ntiles) << 7;
  int bn = (ti % ntiles) << 7;
  int tid = threadIdx.x;
  int wave = tid >> 6, lane = tid & 63;
  int wr = (wave >> 1) << 6, wc = (wave & 1) << 6;
  int la = lane & 15, lq = lane >> 4;
  f32x4 acc[4][4] = {};
  for (int k0 = 0; k0 < K; k0 += 32){
    {
      int r = tid >> 1, ch = (tid & 1) << 4;
      if (mode == 0){
        const uint4* asrc = (const uint4*)(Aq + (size_t)(bm + r)*K + k0 + ch);
        uint4 v0 = asrc[0], v1 = asrc[1];
        *(uint4*)&a_lds[r][ch]     = v0;
        *(uint4*)&a_lds[r][ch + 8] = v1;
      } else {
        int g = bm + r; int b = g / 196; int pp = g - b*196;
        const float4* as = (const float4*)(Af + ((size_t)sidx[b]*196 + pp)*2048 + k0 + ch);
        float4 f0 = as[0], f1 = as[1], f2 = as[2], f3 = as[3];
        *(uint4*)&a_lds[r][ch]     = make_uint4(pack2(f0.x,f0.y), pack2(f0.z,f0.w), pack2(f1.x,f1.y), pack2(f1.z,f1.w));
        *(uint4*)&a_lds[r][ch + 8] = make_uint4(pack2(f2.x,f2.y), pack2(f2.z,f2.w), pack2(f3.x,f3.y), pack2(f3.z,f3.w));
      }
      int kk = tid >> 3, n0 = (tid & 7) << 4;
      const us* bs = Bq + (size_t)(k0 + kk)*N + bn + n0;
      uint4 bv0 = *(const uint4*)bs, bv1 = *(const uint4*)(bs + 8);
      unsigned vals[8] = {bv0.x, bv0.y, bv0.z, bv0.w, bv1.x, bv1.y, bv1.z, bv1.w};
      #pragma unroll
      for (int i = 0; i < 8; i++){
        b_lds[n0 + 2*i][kk]     = (us)(vals[i] & 0xffffu);
        b_lds[n0 + 2*i + 1][kk] = (us)(vals[i] >> 16);
      }
    }
    __syncthreads();
    bf16x8 af[4], bfr[4];
    #pragma unroll
    for (int mt = 0; mt < 4; mt++) af[mt]  = *(const bf16x8*)&a_lds[wr + mt*16 + la][lq*8];
    #pragma unroll
    for (int nt = 0; nt < 4; nt++) bfr[nt] = *(const bf16x8*)&b_lds[wc + nt*16 + la][lq*8];
    #pragma unroll
    for (int mt = 0; mt < 4; mt++)
      #pragma unroll
      for (int nt = 0; nt < 4; nt++)
        acc[mt][nt] = MFMA(af[mt], bfr[nt], acc[mt][nt]);
    __syncthreads();
  }
  #pragma unroll
  for (int mt = 0; mt < 4; mt++){
    int row0 = bm + wr + mt*16 + lq*4;
    #pragma unroll
    for (int nt = 0; nt < 4; nt++){
      int coln = bn + wc + nt*16 + la;
      float bb = bias ? bias[coln] : 0.f;
      #pragma unroll
      for (int r = 0; r < 4; r++){
        float v = acc[mt][nt][r] + bb;
        if (obf) ((us*)C)[(size_t)(row0 + r)*N + coln] = f2bf(v);
        else     C[(size_t)(row0 + r)*N + coln] = v;
      }
    }
  }
}

// ---------------- cooperative scan kernel (8 groups x 32 blocks) ----------------
// Per-group barrier: 4 arrival lines (8 blocks each) -> master line -> flag line.

__device__ __forceinline__ void gsync_g(int* sc, int gen, int jb){
  __syncthreads();
  if (threadIdx.x == 0){
    int old = __hip_atomic_fetch_add(&sc[(jb & 3)*16], 1, __ATOMIC_RELEASE, __HIP_MEMORY_SCOPE_AGENT);
    bool last = false;
    if (old == gen*8 - 1){
      int old2 = __hip_atomic_fetch_add(&sc[64], 1, __ATOMIC_ACQ_REL, __HIP_MEMORY_SCOPE_AGENT);
      if (old2 == gen*4 - 1){
        __builtin_amdgcn_fence(__ATOMIC_ACQ_REL, "agent");
        __hip_atomic_store(&sc[80], gen, __ATOMIC_RELAXED, __HIP_MEMORY_SCOPE_AGENT);
        last = true;
      }
    }
    if (!last){
      while (__hip_atomic_load(&sc[80], __ATOMIC_RELAXED, __HIP_MEMORY_SCOPE_AGENT) < gen)
        __builtin_amdgcn_s_sleep(1);
      __builtin_amdgcn_fence(__ATOMIC_ACQUIRE, "agent");
    }
  }
  __syncthreads();
}

// fc over slots: M=16 tile with 4 valid rows (group batches), writes preds[tpred]
__device__ __forceinline__ void fc_run(const KParams& p, const int* sm_dl, int b0,
                                       int slot, int nslots, int niter,
                                       int la, int lq, int tpred){
  bf16x8 afr[16];
  const us* hp = p.h_bf16 + ((size_t)(b0 + (la & 3)))*512 + lq*8;
  #pragma unroll
  for (int ks = 0; ks < 16; ks++) afr[ks] = *(const bf16x8*)(hp + ks*32);
  for (int it = 0; it < niter; it++){
    int tile = slot + it*nslots;
    if (tile < 625){
      int n0 = tile*16;
      const us* wp = p.Wt + ((size_t)(4608 + n0 + la))*512 + lq*8;
      f32x4 ac = {};
      #pragma unroll
      for (int ks = 0; ks < 16; ks++){
        bf16x8 bB = *(const bf16x8*)(wp + ks*32);
        ac = MFMA(afr[ks], bB, ac);
      }
      if (lq == 0){
        int v = n0 + la;
        float bb = p.fc_b[v];
        #pragma unroll
        for (int r = 0; r < 4; r++){
          bool act = tpred < sm_dl[b0 + r];
          p.out_preds[((size_t)(b0 + r)*T_ + tpred)*V_ + v] = act ? (ac[r] + bb) : 0.f;
        }
      }
    }
  }
}

__global__ void __launch_bounds__(256, 1) k_loop(KParams p){
  const int tid = threadIdx.x, blk = blockIdx.x;
  const int gb = blk >> 5, jb = blk & 31, b0 = gb*4;
  const int wv = tid >> 6, lane = tid & 63, la = lane & 15, lq = lane >> 4;
  int* sc = p.sync + gb*128;
  __shared__ float sm_att2[512], sm_fw[512], sm_red[16];
  __shared__ float sm_a4f[4*PP];
  __shared__ float gq[4][16][4];
  __shared__ int sm_dl[32];
  int gen = 0;

  if (tid < 32) sm_dl[tid] = p.declen[tid];
  __syncthreads();

  // ===== GP1: mean over p (group-local) =====
  {
    int d = jb*64 + (tid >> 2), b = b0 + (tid & 3);
    const uint4* rp = (const uint4*)(p.encT + ((size_t)b*D_ + d)*PP);
    float s = 0.f;
    for (int i = 0; i < 26; i++){
      uint4 u = rp[i];
      s += bf2f(u.x&0xffffu)+bf2f(u.x>>16)+bf2f(u.y&0xffffu)+bf2f(u.y>>16)
         + bf2f(u.z&0xffffu)+bf2f(u.z>>16)+bf2f(u.w&0xffffu)+bf2f(u.w>>16);
    }
    p.mean_bf16[(size_t)b*D_ + d] = f2bf(s*(1.f/196.f));
  }
  gsync_g(sc, ++gen, jb);
  // ===== GP2: h0/c0 = mean @ Wt3 (waves 0,1 per block) =====
  if (wv < 2){
    int tile = jb*2 + wv;
    const us* wp = p.Wt3 + ((size_t)(tile*16 + la))*2048 + lq*8;
    const us* ap = p.mean_bf16 + ((size_t)(b0 + (la & 3)))*2048 + lq*8;
    f32x4 ac0 = {}, ac1 = {};
    for (int ki = 0; ki < 64; ki += 2){
      bf16x8 aA = *(const bf16x8*)(ap + ki*32);
      bf16x8 bB = *(const bf16x8*)(wp + ki*32);
      ac0 = MFMA(aA, bB, ac0);
      bf16x8 aA2 = *(const bf16x8*)(ap + ki*32 + 32);
      bf16x8 bB2 = *(const bf16x8*)(wp + ki*32 + 32);
      ac1 = MFMA(aA2, bB2, ac1);
    }
    f32x4 ac = ac0 + ac1;
    if (lq == 0){
      int col = tile*16 + la;
      #pragma unroll
      for (int r = 0; r < 4; r++){
        if (col < 512) p.h_bf16[(size_t)(b0+r)*512 + col] = f2bf(ac[r] + p.init_h_b[col]);
        else           p.c[(size_t)(b0+r)*512 + col - 512] = ac[r] + p.init_c_b[col - 512];
      }
    }
  }
  gsync_g(sc, ++gen, jb);

  for (int t = 0; t < T_; ++t){
    // ===== G1: s1out[b0..b0+3][0:4608] = h @ Wt (att2|gate|ghh) =====
    {
      bf16x8 afr[16];
      const us* hp = p.h_bf16 + ((size_t)(b0 + (la & 3)))*512 + lq*8;
      #pragma unroll
      for (int ks = 0; ks < 16; ks++) afr[ks] = *(const bf16x8*)(hp + ks*32);
      int slot = jb*4 + wv;
      #pragma unroll
      for (int it = 0; it < 3; it++){
        int tile = slot + it*128;
        if (tile < 288){
          int n0 = tile*16;
          const us* wp = p.Wt + ((size_t)(n0 + la))*512 + lq*8;
          f32x4 ac = {};
          #pragma unroll
          for (int ks = 0; ks < 16; ks++){
            bf16x8 bB = *(const bf16x8*)(wp + ks*32);
            ac = MFMA(afr[ks], bB, ac);
          }
          if (lq == 0){
            #pragma unroll
            for (int r = 0; r < 4; r++) p.s1out[(size_t)(b0+r)*4608 + n0 + la] = ac[r];
          }
        }
      }
    }
    gsync_g(sc, ++gen, jb);
    // ===== G2: blocks 0..3 attention softmax | blocks 4..31 fc preds[t-1] =====
    if (jb < 4){
      int b = b0 + jb;
      for (int cc = tid; cc < 512; cc += 256){
        sm_att2[cc] = p.s1out[(size_t)b*4608 + cc] + p.dec_att_b[cc];
        sm_fw[cc]   = p.full_att_w[cc];
      }
      __syncthreads();
      float ee = -1e30f;
      if (tid < 196){
        const uint4* row = (const uint4*)(p.att1 + ((size_t)(b*196 + tid))*512);
        float s = 0.f;
        #pragma unroll 8
        for (int i = 0; i < 64; i++){
          uint4 u = row[i];
          float4 a0 = *(const float4*)&sm_att2[i*8], a1 = *(const float4*)&sm_att2[i*8+4];
          float4 f0 = *(const float4*)&sm_fw[i*8],   f1 = *(const float4*)&sm_fw[i*8+4];
          s += fmaxf(bf2f(u.x&0xffffu)+a0.x,0.f)*f0.x + fmaxf(bf2f(u.x>>16)+a0.y,0.f)*f0.y
             + fmaxf(bf2f(u.y&0xffffu)+a0.z,0.f)*f0.z + fmaxf(bf2f(u.y>>16)+a0.w,0.f)*f0.w
             + fmaxf(bf2f(u.z&0xffffu)+a1.x,0.f)*f1.x + fmaxf(bf2f(u.z>>16)+a1.y,0.f)*f1.y
             + fmaxf(bf2f(u.w&0xffffu)+a1.z,0.f)*f1.z + fmaxf(bf2f(u.w>>16)+a1.w,0.f)*f1.w;
        }
        ee = s;
      }
      float v = ee;
      #pragma unroll
      for (int off = 32; off; off >>= 1) v = fmaxf(v, __shfl_xor(v, off));
      if (lane == 0) sm_red[wv] = v;
      __syncthreads();
      float m = fmaxf(fmaxf(sm_red[0], sm_red[1]), fmaxf(sm_red[2], sm_red[3]));
      float ex = (tid < 196) ? __expf(ee - m) : 0.f;
      float sv = ex;
      #pragma unroll
      for (int off = 32; off; off >>= 1) sv += __shfl_xor(sv, off);
      if (lane == 0) sm_red[4 + wv] = sv;
      __syncthreads();
      float ssum = sm_red[4] + sm_red[5] + sm_red[6] + sm_red[7];
      if (tid < 196){
        float a = ex/ssum;
        p.alpha_g[b*PP + tid] = a;
        bool act = t < sm_dl[b];
        p.out_alphas[((size_t)b*T_ + t)*P_ + tid] = act ? a : 0.f;
      } else if (tid < PP) p.alpha_g[b*PP + tid] = 0.f;
    } else if (t > 0){
      fc_run(p, sm_dl, b0, (jb - 4)*4 + wv, 112, 6, la, lq, t - 1);
    }
    gsync_g(sc, ++gen, jb);
    // ===== G3: awe = gate * (alpha @ enc), 32 blocks x (64 d x 4 b) =====
    {
      for (int i = tid; i < 4*PP; i += 256) sm_a4f[i] = p.alpha_g[b0*PP + i];
      __syncthreads();
      int d = jb*64 + (tid >> 2), b = b0 + (tid & 3);
      const float* al = sm_a4f + (tid & 3)*PP;
      const uint4* rp = (const uint4*)(p.encT + ((size_t)b*D_ + d)*PP);
      float acc = 0.f;
      for (int i = 0; i < 26; i++){
        uint4 u = rp[i];
        float4 a0 = *(const float4*)(al + i*8), a1 = *(const float4*)(al + i*8 + 4);
        acc += a0.x*bf2f(u.x&0xffffu) + a0.y*bf2f(u.x>>16)
             + a0.z*bf2f(u.y&0xffffu) + a0.w*bf2f(u.y>>16)
             + a1.x*bf2f(u.z&0xffffu) + a1.y*bf2f(u.z>>16)
             + a1.z*bf2f(u.w&0xffffu) + a1.w*bf2f(u.w>>16);
      }
      float gate = sigm(p.s1out[(size_t)b*4608 + 512 + d] + p.f_beta_b[d]);
      p.awe_bf16[(size_t)b*2048 + d] = f2bf(acc*gate);
    }
    gsync_g(sc, ++gen, jb);
    // ===== G4: g = gpre + ghh + awe@Wt2 (gate-sliced per block) + LSTM cell =====
    {
      int q = wv, hc0 = jb*16;
      const us* wp = p.Wt2 + ((size_t)(q*512 + hc0 + la))*2048 + lq*8;
      const us* ap = p.awe_bf16 + ((size_t)(b0 + (la & 3)))*2048 + lq*8;
      f32x4 ac0 = {}, ac1 = {};
      for (int ki = 0; ki < 64; ki += 2){
        bf16x8 aA = *(const bf16x8*)(ap + ki*32);
        bf16x8 bB = *(const bf16x8*)(wp + ki*32);
        ac0 = MFMA(aA, bB, ac0);
        bf16x8 aA2 = *(const bf16x8*)(ap + ki*32 + 32);
        bf16x8 bB2 = *(const bf16x8*)(wp + ki*32 + 32);
        ac1 = MFMA(aA2, bB2, ac1);
      }
      f32x4 ac = ac0 + ac1;
      if (lq == 0){
        #pragma unroll
        for (int r = 0; r < 4; r++) gq[q][la][r] = ac[r];
      }
      __syncthreads();
      if (tid < 64){
        int hc = hc0 + (tid & 15), r = tid >> 4;
        int b = b0 + r;
        float gv[4];
        #pragma unroll
        for (int qq = 0; qq < 4; qq++)
          gv[qq] = gq[qq][tid & 15][r]
                 + p.s1out[(size_t)b*4608 + 2560 + qq*512 + hc]
                 + p.gpre[((size_t)t*32 + b)*2048 + qq*512 + hc];
        float cold = p.c[(size_t)b*512 + hc];
        float cn = sigm(gv[1])*cold + sigm(gv[0])*tanh_f(gv[2]);
        float hn = sigm(gv[3])*tanh_f(cn);
        if (t < sm_dl[b]){
          p.c[(size_t)b*512 + hc] = cn;
          p.h_bf16[(size_t)b*512 + hc] = f2bf(hn);
        }
      }
    }
    gsync_g(sc, ++gen, jb);
  }
  // ===== epilogue: preds[T-1] (all 32 blocks per group) =====
  fc_run(p, sm_dl, b0, jb*4 + wv, 128, 5, la, lq, T_ - 1);
}

// ---------------- host launcher ----------------

extern "C" void kernel_launch(void* const* d_in, const int* in_sizes, int n_in,
                              void* d_out, int out_size, void* d_ws, size_t ws_size,
                              hipStream_t stream){
  (void)in_sizes; (void)n_in; (void)out_size; (void)ws_size;
  KParams p;
  p.encoder_out = (const float*)d_in[0];
  p.captions    = (const int*)d_in[1];
  p.cap_lens    = (const int*)d_in[2];
  p.enc_att_w   = (const float*)d_in[3];  p.enc_att_b = (const float*)d_in[4];
  p.dec_att_w   = (const float*)d_in[5];  p.dec_att_b = (const float*)d_in[6];
  p.full_att_w  = (const float*)d_in[7];  p.full_att_b = (const float*)d_in[8];
  p.emb         = (const float*)d_in[9];
  p.init_h_w    = (const float*)d_in[10]; p.init_h_b = (const float*)d_in[11];
  p.init_c_w    = (const float*)d_in[12]; p.init_c_b = (const float*)d_in[13];
  p.f_beta_w    = (const float*)d_in[14]; p.f_beta_b = (const float*)d_in[15];
  p.lstm_w_ih   = (const float*)d_in[16]; p.lstm_w_hh = (const float*)d_in[17]; p.lstm_b = (const float*)d_in[18];
  p.fc_w        = (const float*)d_in[19]; p.fc_b = (const float*)d_in[20];

  float* out = (float*)d_out;
  p.out_preds   = out;
  p.out_caps    = out + 6400000;
  p.out_declens = out + 6400672;
  p.out_alphas  = out + 6400704;
  p.out_sortind = out + 6526144;

  char* w = (char*)d_ws; size_t off = 0;
  auto alloc = [&](size_t bytes)->char*{ char* r = w + off; off = (off + bytes + 255) & ~(size_t)255; return r; };
  p.sort_ind  = (int*)alloc(128);
  p.declen    = (int*)alloc(128);
  p.caps_s    = (int*)alloc(2688);
  p.h_bf16    = (us*)alloc(32768);
  p.c         = (float*)alloc(65536);
  p.mean_bf16 = (us*)alloc(131072);
  p.waw_bf16  = (us*)alloc(2097152);
  p.wihE_bf16 = (us*)alloc(2097152);
  p.embs_bf16 = (us*)alloc(655360);
  p.att1      = (us*)alloc(6422528);     // [6272][512] bf16
  p.Wt        = (us*)alloc(14958592);    // [14608][512] bf16
  p.Wt2       = (us*)alloc(8388608);     // [2048][2048] bf16
  p.Wt3       = (us*)alloc(4194304);     // [1024][2048] bf16
  p.encT      = (us*)alloc(27262976);    // [32][2048][208] bf16
  p.gpre      = (float*)alloc(5242880);  // [20][32][2048]
  p.s1out     = (float*)alloc(589824);   // [32][4608]
  p.alpha_g   = (float*)alloc(26624);    // [32][208]
  p.awe_bf16  = (us*)alloc(131072);      // [32][2048]
  p.sync      = (int*)alloc(4096);       // 8 groups x 128 ints

  hipMemsetAsync(p.sync, 0, 4096, stream);
  hipLaunchKernelGGL(k_meta,  dim3(1),    dim3(64),  0, stream, p);
  hipLaunchKernelGGL(k_prep,  dim3(8296), dim3(256), 0, stream, p);
  hipLaunchKernelGGL(k_gemm2, dim3(276),  dim3(256), 0, stream, p);
  void* args[] = { (void*)&p };
  hipLaunchCooperativeKernel((void*)k_loop, dim3(256), dim3(256), args, 0, stream);
}